// Round 14
// baseline (374.722 us; speedup 1.0000x reference)
//
#include <hip/hip_runtime.h>
#include <math.h>

#define N_NODES 64512
#define DIN 84
#define XHP 96           /* padded fp16 row: 192 B = 3 aligned cache lines */
#define KP 96            /* MFMA K padded to 96 = 3 x 32 */
#define USP 104          /* LDS us pitch (f16) -> bank-spread for b128 reads */
#define DH 128
#define NPG 1008
#define BG 64
#define NSNAP 12
#define NSEG 84
#define NEDGE (N_NODES * 16)
#define DEGCAP 64
#define NBUCK 252        /* dst>>8 buckets; 64512 = 252*256 */
#define EPB 4096         /* edges per epart block; NEDGE/EPB = 252 exactly */
#define BCAP 4608        /* per-bucket record capacity */
#define ATT_SCALE 0.08838834764831845f /* 1/sqrt(128) */

typedef __bf16 bf16_t;
typedef __bf16 bf16x8 __attribute__((ext_vector_type(8)));
typedef __bf16 bf16x4 __attribute__((ext_vector_type(4)));
typedef float f32x4 __attribute__((ext_vector_type(4)));
typedef _Float16 f16_t;
typedef _Float16 f16x4 __attribute__((ext_vector_type(4)));
typedef _Float16 f16x8 __attribute__((ext_vector_type(8)));

__device__ __forceinline__ f32x4 up4(f16x4 v) {
    return (f32x4){(float)v[0], (float)v[1], (float)v[2], (float)v[3]};
}

// ---------------------------------------------------------------------------
// cvt_xh: x -> fp16 copy into padded rows (stride 96); zero bucket tails.
// ---------------------------------------------------------------------------
__global__ __launch_bounds__(256) void cvt_xh(const float* __restrict__ x,
                                              f16_t* __restrict__ xh,
                                              int* __restrict__ bucketTail) {
    int t = blockIdx.x * 256 + threadIdx.x;
    if (t < N_NODES * 21) {
        int node = t / 21;
        int c = t - node * 21;
        f32x4 v = *(const f32x4*)(x + (size_t)node * DIN + c * 4);
        f16x4 o;
        o[0] = (f16_t)v[0]; o[1] = (f16_t)v[1];
        o[2] = (f16_t)v[2]; o[3] = (f16_t)v[3];
        *(f16x4*)(xh + (size_t)node * XHP + c * 4) = o;
    }
    if (t * 4 < NBUCK) {
        int4 z = {0, 0, 0, 0};
        *(int4*)(bucketTail + t * 4) = z;
    }
}

// ---------------------------------------------------------------------------
// epart: partition edges into 252 dst-buckets (LDS histogram, one global
// atomic per (block,bucket)). Record = (dst:u16 << 16) | src:u16.
// ---------------------------------------------------------------------------
__global__ __launch_bounds__(256) void epart(const int* __restrict__ src,
                                             const int* __restrict__ dst,
                                             int* __restrict__ bucketTail,
                                             unsigned int* __restrict__ rec) {
    __shared__ int lcnt[NBUCK];
    __shared__ int gbase[NBUCK];
    int tid = threadIdx.x;
    int e0 = blockIdx.x * EPB;
    for (int i = tid; i < NBUCK; i += 256) lcnt[i] = 0;
    __syncthreads();

    unsigned int r[16];
    unsigned short lp[16];
    unsigned short bk[16];
#pragma unroll
    for (int i = 0; i < 16; i++) {
        int e = e0 + tid + i * 256;  // coalesced
        int s = src[e], d = dst[e];
        r[i] = ((unsigned int)d << 16) | (unsigned int)s;
        int b = d >> 8;
        bk[i] = (unsigned short)b;
        lp[i] = (unsigned short)atomicAdd(&lcnt[b], 1);
    }
    __syncthreads();
    for (int i = tid; i < NBUCK; i += 256)
        gbase[i] = atomicAdd(&bucketTail[i], lcnt[i]);
    __syncthreads();
#pragma unroll
    for (int i = 0; i < 16; i++) {
        int b = bk[i];
        int g = gbase[b] + lp[i];
        if (g < BCAP) rec[(size_t)b * BCAP + g] = r[i];
    }
}

// ---------------------------------------------------------------------------
// ebuild: padded-CSR per 256-node bucket in LDS, edge lists grouped by
// src-range (src>>13) for chip-wide gather locality.
// ---------------------------------------------------------------------------
__global__ __launch_bounds__(256) void ebuild(const unsigned int* __restrict__ rec,
                                              const int* __restrict__ bucketTail,
                                              int* __restrict__ cnt,
                                              unsigned short* __restrict__ eidx) {
    __shared__ unsigned short stage[256 * 72];
    __shared__ int rb8[256 * 8];
    int tid = threadIdx.x;
    int b = blockIdx.x;
#pragma unroll
    for (int i = 0; i < 8; i++) rb8[tid + i * 256] = 0;
    __syncthreads();

    int n = min(bucketTail[b], BCAP);
    const unsigned int* rbp = rec + (size_t)b * BCAP;
    for (int i = tid; i < n; i += 256) {
        unsigned int rv = rbp[i];
        int ld = (rv >> 16) & 255;
        int rng = (rv & 0xffffu) >> 13;
        atomicAdd(&rb8[ld * 8 + rng], 1);
    }
    __syncthreads();
    {
        int s = 0;
#pragma unroll
        for (int r = 0; r < 8; r++) {
            int c = rb8[tid * 8 + r];
            rb8[tid * 8 + r] = s;
            s += c;
        }
        cnt[b * 256 + tid] = s;
    }
    __syncthreads();
    for (int i = tid; i < n; i += 256) {
        unsigned int rv = rbp[i];
        int ld = (rv >> 16) & 255;
        int rng = (rv & 0xffffu) >> 13;
        int p = atomicAdd(&rb8[ld * 8 + rng], 1);
        if (p < DEGCAP) stage[ld * 72 + p] = (unsigned short)(rv & 0xffffu);
    }
    __syncthreads();

    uint4* op = (uint4*)(eidx + (size_t)b * 256 * DEGCAP);
#pragma unroll
    for (int i = 0; i < 8; i++) {
        int ch = tid + i * 256;
        int node = ch >> 3, e0 = (ch & 7) << 3;
        op[ch] = *(const uint4*)&stage[node * 72 + e0];
    }
}

// ---------------------------------------------------------------------------
// prep: bvec = b1 @ w2 (f32); w1hT, w12hT = transposed fp16 weights
// [128 dims][96 k] (k-major per dim = MFMA B-fragment layout, zero-padded).
// ---------------------------------------------------------------------------
__global__ __launch_bounds__(128) void prep_w12(const float* __restrict__ w1,
                                                const float* __restrict__ w2,
                                                const float* __restrict__ b1,
                                                f16_t* __restrict__ w1hT,
                                                f16_t* __restrict__ w12hT,
                                                float* __restrict__ bvec) {
    __shared__ float rowv[DH];
    int r = blockIdx.x;
    int j = threadIdx.x;
    const float* srcv = (r < DIN) ? (w1 + (size_t)r * DH) : b1;
    rowv[j] = srcv[j];
    __syncthreads();
    float acc = 0.f;
#pragma unroll 4
    for (int k = 0; k < DH; k++) acc += rowv[k] * w2[k * DH + j];
    if (r < DIN) {
        w12hT[j * KP + r] = (f16_t)acc;
        w1hT[j * KP + r] = (f16_t)w1[(size_t)r * DH + j];
    } else {
        bvec[j] = acc;
        for (int k = DIN; k < KP; k++) {
            w1hT[j * KP + k] = (f16_t)0.f;
            w12hT[j * KP + k] = (f16_t)0.f;
        }
    }
}

// ---------------------------------------------------------------------------
// gin1: fused gather(fp16 x) + MFMA linear1 (16x16x32 f16, K=96).
// 512 threads / 32 nodes. Persists z as fp16 (zh).
// ---------------------------------------------------------------------------
__global__ __launch_bounds__(512) void gin1(const float* __restrict__ x,
                                            const f16_t* __restrict__ xh,
                                            const int* __restrict__ cnt,
                                            const unsigned short* __restrict__ eidx,
                                            const f16_t* __restrict__ w1hT,
                                            const float* __restrict__ b1,
                                            float* __restrict__ h1,
                                            f16_t* __restrict__ zh) {
    __shared__ f16_t us[32][USP];
    int n0 = blockIdx.x * 32;
    int tid = threadIdx.x;
    int grp = tid >> 4;
    int gl = tid & 15;
    int node = n0 + grp;
    int s = node * DEGCAP;
    int e = s + min(cnt[node], DEGCAP);
    bool has2 = gl < 5;

    const float* xn = x + (size_t)node * DIN;
    f32x4 a0 = *(const f32x4*)(xn + gl * 4);
    f32x4 a1 = has2 ? *(const f32x4*)(xn + 64 + gl * 4) : (f32x4){0.f, 0.f, 0.f, 0.f};

    int i = s;
    for (; i + 4 <= e; i += 4) {
        const f16_t* p0 = xh + (size_t)eidx[i] * XHP + gl * 4;
        const f16_t* p1 = xh + (size_t)eidx[i + 1] * XHP + gl * 4;
        const f16_t* p2 = xh + (size_t)eidx[i + 2] * XHP + gl * 4;
        const f16_t* p3 = xh + (size_t)eidx[i + 3] * XHP + gl * 4;
        a0 += up4(*(const f16x4*)p0) + up4(*(const f16x4*)p1) +
              up4(*(const f16x4*)p2) + up4(*(const f16x4*)p3);
        if (has2) {
            a1 += up4(*(const f16x4*)(p0 + 64)) + up4(*(const f16x4*)(p1 + 64)) +
                  up4(*(const f16x4*)(p2 + 64)) + up4(*(const f16x4*)(p3 + 64));
        }
    }
    for (; i < e; i++) {
        const f16_t* p0 = xh + (size_t)eidx[i] * XHP + gl * 4;
        a0 += up4(*(const f16x4*)p0);
        if (has2) a1 += up4(*(const f16x4*)(p0 + 64));
    }

    // z in fp16: persist to zh AND stage into us for the MFMA linear
    f16x4 z0;
    z0[0] = (f16_t)a0[0]; z0[1] = (f16_t)a0[1];
    z0[2] = (f16_t)a0[2]; z0[3] = (f16_t)a0[3];
    *(f16x4*)(zh + (size_t)node * XHP + gl * 4) = z0;
    *(f16x4*)&us[grp][gl * 4] = z0;
    if (has2) {
        f16x4 z1;
        z1[0] = (f16_t)a1[0]; z1[1] = (f16_t)a1[1];
        z1[2] = (f16_t)a1[2]; z1[3] = (f16_t)a1[3];
        *(f16x4*)(zh + (size_t)node * XHP + 64 + gl * 4) = z1;
        *(f16x4*)&us[grp][64 + gl * 4] = z1;
    }
    if (gl >= 5 && gl < 8) {  // zero K-padding cols 84..95
        f16x4 zz = {(f16_t)0.f, (f16_t)0.f, (f16_t)0.f, (f16_t)0.f};
        *(f16x4*)&us[grp][64 + gl * 4] = zz;
    }
    __syncthreads();

    // MFMA linear: wave wv owns dims wv*16..wv*16+15, both 16-node tiles
    int wv = tid >> 6, lane = tid & 63;
    int l15 = lane & 15, quad = lane >> 4;
    int dim = wv * 16 + l15;
    f32x4 acc[2];
    acc[0] = (f32x4){0.f, 0.f, 0.f, 0.f};
    acc[1] = (f32x4){0.f, 0.f, 0.f, 0.f};
#pragma unroll
    for (int ks = 0; ks < 3; ks++) {
        f16x8 bW = *(const f16x8*)(w1hT + (size_t)dim * KP + ks * 32 + quad * 8);
        f16x8 aU0 = *(const f16x8*)&us[l15][ks * 32 + quad * 8];
        f16x8 aU1 = *(const f16x8*)&us[16 + l15][ks * 32 + quad * 8];
        acc[0] = __builtin_amdgcn_mfma_f32_16x16x32_f16(aU0, bW, acc[0], 0, 0, 0);
        acc[1] = __builtin_amdgcn_mfma_f32_16x16x32_f16(aU1, bW, acc[1], 0, 0, 0);
    }
    float bias = b1[dim];
#pragma unroll
    for (int tm = 0; tm < 2; tm++) {
        int nb = n0 + tm * 16 + quad * 4;
#pragma unroll
        for (int r = 0; r < 4; r++)
            h1[(size_t)(nb + r) * DH + dim] = acc[tm][r] + bias;
    }
}

// ---------------------------------------------------------------------------
// gin2: gather z (fp16) + MFMA linear (W12, K=96) + deg-bias + pe.
// ---------------------------------------------------------------------------
__global__ __launch_bounds__(512) void gin2(const f16_t* __restrict__ zh,
                                            const int* __restrict__ cnt,
                                            const unsigned short* __restrict__ eidx,
                                            const f16_t* __restrict__ w12hT,
                                            const float* __restrict__ bvec,
                                            const float* __restrict__ b2,
                                            const float* __restrict__ pe,
                                            bf16_t* __restrict__ h2bf,
                                            bf16_t* __restrict__ h2T) {
    __shared__ f16_t us[32][USP];
    __shared__ float sdeg[32];
    int n0 = blockIdx.x * 32;
    int tid = threadIdx.x;
    int grp = tid >> 4;
    int gl = tid & 15;
    int node = n0 + grp;
    int dg = min(cnt[node], DEGCAP);
    int s = node * DEGCAP;
    int e = s + dg;
    bool has2 = gl < 5;
    if (gl == 0) sdeg[grp] = (float)(1 + dg);

    const f16_t* zn = zh + (size_t)node * XHP;
    f32x4 a0 = up4(*(const f16x4*)(zn + gl * 4));
    f32x4 a1 = has2 ? up4(*(const f16x4*)(zn + 64 + gl * 4)) : (f32x4){0.f, 0.f, 0.f, 0.f};

    int i = s;
    for (; i + 4 <= e; i += 4) {
        const f16_t* p0 = zh + (size_t)eidx[i] * XHP + gl * 4;
        const f16_t* p1 = zh + (size_t)eidx[i + 1] * XHP + gl * 4;
        const f16_t* p2 = zh + (size_t)eidx[i + 2] * XHP + gl * 4;
        const f16_t* p3 = zh + (size_t)eidx[i + 3] * XHP + gl * 4;
        a0 += up4(*(const f16x4*)p0) + up4(*(const f16x4*)p1) +
              up4(*(const f16x4*)p2) + up4(*(const f16x4*)p3);
        if (has2) {
            a1 += up4(*(const f16x4*)(p0 + 64)) + up4(*(const f16x4*)(p1 + 64)) +
                  up4(*(const f16x4*)(p2 + 64)) + up4(*(const f16x4*)(p3 + 64));
        }
    }
    for (; i < e; i++) {
        const f16_t* p0 = zh + (size_t)eidx[i] * XHP + gl * 4;
        a0 += up4(*(const f16x4*)p0);
        if (has2) a1 += up4(*(const f16x4*)(p0 + 64));
    }
    f16x4 u0;
    u0[0] = (f16_t)a0[0]; u0[1] = (f16_t)a0[1];
    u0[2] = (f16_t)a0[2]; u0[3] = (f16_t)a0[3];
    *(f16x4*)&us[grp][gl * 4] = u0;
    if (has2) {
        f16x4 u1;
        u1[0] = (f16_t)a1[0]; u1[1] = (f16_t)a1[1];
        u1[2] = (f16_t)a1[2]; u1[3] = (f16_t)a1[3];
        *(f16x4*)&us[grp][64 + gl * 4] = u1;
    }
    if (gl >= 5 && gl < 8) {
        f16x4 zz = {(f16_t)0.f, (f16_t)0.f, (f16_t)0.f, (f16_t)0.f};
        *(f16x4*)&us[grp][64 + gl * 4] = zz;
    }
    __syncthreads();

    int wv = tid >> 6, lane = tid & 63;
    int l15 = lane & 15, quad = lane >> 4;
    int dim = wv * 16 + l15;
    f32x4 acc[2];
    acc[0] = (f32x4){0.f, 0.f, 0.f, 0.f};
    acc[1] = (f32x4){0.f, 0.f, 0.f, 0.f};
#pragma unroll
    for (int ks = 0; ks < 3; ks++) {
        f16x8 bW = *(const f16x8*)(w12hT + (size_t)dim * KP + ks * 32 + quad * 8);
        f16x8 aU0 = *(const f16x8*)&us[l15][ks * 32 + quad * 8];
        f16x8 aU1 = *(const f16x8*)&us[16 + l15][ks * 32 + quad * 8];
        acc[0] = __builtin_amdgcn_mfma_f32_16x16x32_f16(aU0, bW, acc[0], 0, 0, 0);
        acc[1] = __builtin_amdgcn_mfma_f32_16x16x32_f16(aU1, bW, acc[1], 0, 0, 0);
    }

    float bb = b2[dim];
    float bv = bvec[dim];
#pragma unroll
    for (int tm = 0; tm < 2; tm++) {
        int nb = n0 + tm * 16 + quad * 4;  // 4-aligned; 4 | 1008 -> same graph
        int bg = nb / NPG;
        int pos = nb - bg * NPG;
        bf16x4 tv;
#pragma unroll
        for (int r = 0; r < 4; r++) {
            float v = acc[tm][r] + bb + sdeg[tm * 16 + quad * 4 + r] * bv +
                      pe[(size_t)(pos + r) * DH + dim];
            bf16_t vb = (bf16_t)v;
            h2bf[(size_t)(nb + r) * DH + dim] = vb;
            tv[r] = vb;
        }
        *(bf16x4*)(h2T + ((size_t)bg * DH + dim) * NPG + pos) = tv;
    }
}

// ---------------------------------------------------------------------------
// Flash MFMA attention: QTILE=256 (8 waves x 2 q-sets), grid 256, XCD
// swizzle, T14 reg-staging + double-buffered Ks/Kt, one barrier per tile.
// Ps wave-private (dedicated region). LDS 129024 B, 1 block/CU.
// ---------------------------------------------------------------------------
#define QTILE 256
#define KTILE 64
#define KS_PITCH 152
#define KT_PITCH 88
#define PS_PITCH 88
#define KSSZ 9728               /* elems: 64*152 */
#define KTSZ 11264              /* elems: 128*88 */
#define BUFSZ (KSSZ + KTSZ)     /* 20992 elems per buffer */
#define PS2_OFF (2 * BUFSZ)     /* 41984 elems */

__global__ __launch_bounds__(512, 1) void attn_mfma(const bf16_t* __restrict__ h2bf,
                                                    const bf16_t* __restrict__ h2T,
                                                    float* __restrict__ ctx) {
    __shared__ __align__(16) bf16_t smem[PS2_OFF + QTILE * PS_PITCH];  // 129024 B

    int tid = threadIdx.x;
    int wv = tid >> 6, lane = tid & 63;
    int l15 = lane & 15, quad = lane >> 4;
    // swizzle: idx = xcd | qt<<3 | bhi<<5 ; b = bhi*8 + xcd (grid 256)
    int idx = blockIdx.x;
    int xcd = idx & 7;
    int qt = (idx >> 3) & 3;
    int b = (idx >> 5) * 8 + xcd;
    const bf16_t* hb = h2bf + (size_t)b * NPG * DH;
    const bf16_t* hbT = h2T + (size_t)b * DH * NPG;

    // ---- Q B-fragments: wave wv owns q-rows qt*256 + wv*32 + set*16 + l15 ----
    bf16x8 bQ[2][4];
#pragma unroll
    for (int set = 0; set < 2; set++) {
        int qrow_frag = qt * QTILE + wv * 32 + set * 16 + l15;
        int qsrc = (qrow_frag < NPG) ? qrow_frag : 0;
#pragma unroll
        for (int kb = 0; kb < 4; kb++)
            bQ[set][kb] = *(const bf16x8*)(hb + (size_t)qsrc * DH + kb * 32 + quad * 8);
    }

    float m0 = -1e30f, li0 = 0.0f;
    float m1 = -1e30f, li1 = 0.0f;
    f32x4 O[2][8];
#pragma unroll
    for (int t = 0; t < 8; t++) {
        O[0][t] = (f32x4){0.f, 0.f, 0.f, 0.f};
        O[1][t] = (f32x4){0.f, 0.f, 0.f, 0.f};
    }

    // staging registers for the async split (4 x uint4 per thread)
    uint4 rK[2], rT[2];
#define LOADR(KT_)                                                              \
    {                                                                           \
        int kt_ = (KT_);                                                        \
        _Pragma("unroll")                                                       \
        for (int i = 0; i < 2; i++) {                                           \
            int c = tid + i * 512;                                              \
            int row = c >> 4, seg = c & 15;                                     \
            int key = kt_ * KTILE + row;                                        \
            uint4 v = {0u, 0u, 0u, 0u};                                         \
            if (key < NPG) v = *(const uint4*)(hb + (size_t)key * DH + seg * 8);\
            rK[i] = v;                                                          \
        }                                                                       \
        _Pragma("unroll")                                                       \
        for (int i = 0; i < 2; i++) {                                           \
            int c = tid + i * 512;                                              \
            int dim = c >> 3, kc = c & 7;                                       \
            int key0 = kt_ * KTILE + kc * 8;                                    \
            uint4 v = {0u, 0u, 0u, 0u};                                         \
            if (key0 < NPG) v = *(const uint4*)(hbT + (size_t)dim * NPG + key0);\
            rT[i] = v;                                                          \
        }                                                                       \
    }
#define DRAIN(BUFOFF_)                                                          \
    {                                                                           \
        int bo_ = (BUFOFF_);                                                    \
        _Pragma("unroll")                                                       \
        for (int i = 0; i < 2; i++) {                                           \
            int c = tid + i * 512;                                              \
            int row = c >> 4, seg = c & 15;                                     \
            *(uint4*)&smem[bo_ + row * KS_PITCH + seg * 8] = rK[i];             \
        }                                                                       \
        _Pragma("unroll")                                                       \
        for (int i = 0; i < 2; i++) {                                           \
            int c = tid + i * 512;                                              \
            int dim = c >> 3, kc = c & 7;                                       \
            *(uint4*)&smem[bo_ + KSSZ + dim * KT_PITCH + kc * 8] = rT[i];       \
        }                                                                       \
    }

    // prologue: tile 0 into buf0; issue tile 1 loads
    LOADR(0);
    DRAIN(0);
    LOADR(1);
    __syncthreads();

    for (int kt = 0; kt < 16; kt++) {
        int bo = (kt & 1) * BUFSZ;
        // drain next tile into the other buffer (overlaps compute across waves)
        if (kt < 15) DRAIN(((kt + 1) & 1) * BUFSZ);
        if (kt < 14) LOADR(kt + 2);

        // ---- S^T = K Q^T (buf[cur] Ks); each aK feeds both q-sets ----
        f32x4 S[2][4];
#pragma unroll
        for (int nt = 0; nt < 4; nt++) {
            S[0][nt] = (f32x4){0.f, 0.f, 0.f, 0.f};
            S[1][nt] = (f32x4){0.f, 0.f, 0.f, 0.f};
#pragma unroll
            for (int kb = 0; kb < 4; kb++) {
                bf16x8 aK = *(const bf16x8*)&smem[bo + (nt * 16 + l15) * KS_PITCH + kb * 32 + quad * 8];
                S[0][nt] = __builtin_amdgcn_mfma_f32_16x16x32_bf16(aK, bQ[0][kb], S[0][nt], 0, 0, 0);
                S[1][nt] = __builtin_amdgcn_mfma_f32_16x16x32_bf16(aK, bQ[1][kb], S[1][nt], 0, 0, 0);
            }
        }

        // ---- scale + mask + online softmax (both sets) ----
        float pmax0 = -1e30f, pmax1 = -1e30f;
#pragma unroll
        for (int nt = 0; nt < 4; nt++) {
            bool valid = (kt * KTILE + nt * 16) < NPG;  // 1008 = 63*16
#pragma unroll
            for (int r = 0; r < 4; r++) {
                float v0 = valid ? S[0][nt][r] * ATT_SCALE : -1e30f;
                float v1 = valid ? S[1][nt][r] * ATT_SCALE : -1e30f;
                S[0][nt][r] = v0;
                S[1][nt][r] = v1;
                pmax0 = fmaxf(pmax0, v0);
                pmax1 = fmaxf(pmax1, v1);
            }
        }
        pmax0 = fmaxf(pmax0, __shfl_xor(pmax0, 16));
        pmax0 = fmaxf(pmax0, __shfl_xor(pmax0, 32));
        pmax1 = fmaxf(pmax1, __shfl_xor(pmax1, 16));
        pmax1 = fmaxf(pmax1, __shfl_xor(pmax1, 32));
        float newm0 = fmaxf(m0, pmax0);
        float newm1 = fmaxf(m1, pmax1);

        float alpha0 = 1.0f, alpha1 = 1.0f;
        // exact defer: rescale only if some lane's running max grew
        if (!__all((newm0 == m0) && (newm1 == m1))) {
            alpha0 = __expf(m0 - newm0);
            alpha1 = __expf(m1 - newm1);
            float a00 = __shfl(alpha0, quad * 4 + 0);
            float a01 = __shfl(alpha0, quad * 4 + 1);
            float a02 = __shfl(alpha0, quad * 4 + 2);
            float a03 = __shfl(alpha0, quad * 4 + 3);
            float a10 = __shfl(alpha1, quad * 4 + 0);
            float a11 = __shfl(alpha1, quad * 4 + 1);
            float a12 = __shfl(alpha1, quad * 4 + 2);
            float a13 = __shfl(alpha1, quad * 4 + 3);
#pragma unroll
            for (int t = 0; t < 8; t++) {
                O[0][t][0] *= a00; O[0][t][1] *= a01; O[0][t][2] *= a02; O[0][t][3] *= a03;
                O[1][t][0] *= a10; O[1][t][1] *= a11; O[1][t][2] *= a12; O[1][t][3] *= a13;
            }
        }
        m0 = newm0;
        m1 = newm1;

        float psum0 = 0.f, psum1 = 0.f;
#pragma unroll
        for (int nt = 0; nt < 4; nt++) {
            bf16x4 pk0, pk1;
#pragma unroll
            for (int r = 0; r < 4; r++) {
                float p0 = __expf(S[0][nt][r] - newm0);
                float p1 = __expf(S[1][nt][r] - newm1);
                psum0 += p0;
                psum1 += p1;
                pk0[r] = (bf16_t)p0;
                pk1[r] = (bf16_t)p1;
            }
            *(bf16x4*)&smem[PS2_OFF + (wv * 32 + l15) * PS_PITCH + nt * 16 + quad * 4] = pk0;
            *(bf16x4*)&smem[PS2_OFF + (wv * 32 + 16 + l15) * PS_PITCH + nt * 16 + quad * 4] = pk1;
        }
        psum0 += __shfl_xor(psum0, 16);
        psum0 += __shfl_xor(psum0, 32);
        psum1 += __shfl_xor(psum1, 16);
        psum1 += __shfl_xor(psum1, 32);
        li0 = li0 * alpha0 + psum0;
        li1 = li1 * alpha1 + psum1;

        // ---- O += P V (Ps wave-private; buf[cur] Kt) ----
#pragma unroll
        for (int kb2 = 0; kb2 < 2; kb2++) {
            bf16x8 aP0 = *(const bf16x8*)&smem[PS2_OFF + (wv * 32 + l15) * PS_PITCH + kb2 * 32 + quad * 8];
            bf16x8 aP1 = *(const bf16x8*)&smem[PS2_OFF + (wv * 32 + 16 + l15) * PS_PITCH + kb2 * 32 + quad * 8];
#pragma unroll
            for (int t = 0; t < 8; t++) {
                bf16x8 bV = *(const bf16x8*)&smem[bo + KSSZ + (t * 16 + l15) * KT_PITCH + kb2 * 32 + quad * 8];
                O[0][t] = __builtin_amdgcn_mfma_f32_16x16x32_bf16(aP0, bV, O[0][t], 0, 0, 0);
                O[1][t] = __builtin_amdgcn_mfma_f32_16x16x32_bf16(aP1, bV, O[1][t], 0, 0, 0);
            }
        }

        __syncthreads();  // buf[cur] reads done; buf[cur^1] writes visible
    }
#undef LOADR
#undef DRAIN

    // ---- epilogue ----
    float invl0[4], invl1[4];
#pragma unroll
    for (int r = 0; r < 4; r++) {
        invl0[r] = 1.0f / __shfl(li0, quad * 4 + r);
        invl1[r] = 1.0f / __shfl(li1, quad * 4 + r);
    }
    float* cb = ctx + (size_t)b * NPG * DH;
#pragma unroll
    for (int t = 0; t < 8; t++)
#pragma unroll
        for (int r = 0; r < 4; r++) {
            int qrow0 = qt * QTILE + wv * 32 + quad * 4 + r;
            int qrow1 = qrow0 + 16;
            if (qrow0 < NPG) cb[(size_t)qrow0 * DH + t * 16 + l15] = O[0][t][r] * invl0[r];
            if (qrow1 < NPG) cb[(size_t)qrow1 * DH + t * 16 + l15] = O[1][t][r] * invl1[r];
        }
}

// ---------------------------------------------------------------------------
// pooling: segmented max/mean -> feat[B,12,512]; blocks 0..255 init y1raw
// ---------------------------------------------------------------------------
__global__ __launch_bounds__(128) void pooling(const float* __restrict__ h1,
                                               const float* __restrict__ ctx,
                                               const float* __restrict__ bf1,
                                               float* __restrict__ feat,
                                               float* __restrict__ y1raw) {
    int bs = blockIdx.x;
    int d = threadIdx.x;
    if (bs < 256) {
        int i = bs * 128 + d;
        y1raw[i] = bf1[i & 511];
    }
    int base = bs * NSEG;
    float mx1 = -1e30f, sm1 = 0.f, mx2 = -1e30f, sm2 = 0.f;
    for (int n = 0; n < NSEG; n++) {
        float v1 = h1[(size_t)(base + n) * DH + d];
        mx1 = fmaxf(mx1, v1);
        sm1 += v1;
        float v2 = ctx[(size_t)(base + n) * DH + d];
        mx2 = fmaxf(mx2, v2);
        sm2 += v2;
    }
    const float invs = 1.0f / NSEG;
    feat[bs * 512 + d] = mx1;
    feat[bs * 512 + 128 + d] = sm1 * invs;
    feat[bs * 512 + 256 + d] = mx2;
    feat[bs * 512 + 384 + d] = sm2 * invs;
}

// ---------------------------------------------------------------------------
// mlp1: split-K GEMM, fp32 atomic accumulation into bias-initialized y1raw
// ---------------------------------------------------------------------------
#define MLP1_KCH 96
__global__ __launch_bounds__(256) void mlp1_splitk(const float* __restrict__ feat,
                                                   const float* __restrict__ wf1,
                                                   float* __restrict__ y1raw) {
    __shared__ float fl[64][MLP1_KCH];
    int k0 = blockIdx.y * MLP1_KCH;
    int tid = threadIdx.x;
    for (int c = tid; c < 64 * MLP1_KCH; c += 256) {
        int row = c / MLP1_KCH;
        int kk = c - row * MLP1_KCH;
        fl[row][kk] = feat[(size_t)row * 6144 + k0 + kk];
    }
    __syncthreads();
    int col = blockIdx.x * 128 + (tid & 127);
    int rbase = (tid >> 7) * 32;
    float acc[32];
#pragma unroll
    for (int r = 0; r < 32; r++) acc[r] = 0.f;
    for (int kg = 0; kg < MLP1_KCH; kg += 4) {
        float w0 = wf1[(size_t)(k0 + kg + 0) * 512 + col];
        float w1 = wf1[(size_t)(k0 + kg + 1) * 512 + col];
        float w2 = wf1[(size_t)(k0 + kg + 2) * 512 + col];
        float w3 = wf1[(size_t)(k0 + kg + 3) * 512 + col];
#pragma unroll
        for (int r = 0; r < 32; r++) {
            float4 f = *(const float4*)&fl[rbase + r][kg];
            acc[r] += f.x * w0 + f.y * w1 + f.z * w2 + f.w * w3;
        }
    }
#pragma unroll
    for (int r = 0; r < 32; r++)
        atomicAdd(&y1raw[(size_t)(rbase + r) * 512 + col], acc[r]);
}

// ---------------------------------------------------------------------------
// head_tail: BN1(silu) -> mlp2 -> BN2 -> mlp3 -> softmax, one block.
// mlp2 inner loop VECTORIZED (float4 zsm reads: 1024 -> 256 LDS ops/thread).
// ---------------------------------------------------------------------------
__global__ __launch_bounds__(1024) void head_tail(const float* __restrict__ y1raw,
                                                  const float* __restrict__ g1,
                                                  const float* __restrict__ be1,
                                                  const float* __restrict__ wf2,
                                                  const float* __restrict__ bf2,
                                                  const float* __restrict__ g2,
                                                  const float* __restrict__ be2,
                                                  const float* __restrict__ wf3,
                                                  const float* __restrict__ bf3,
                                                  float* __restrict__ out) {
    __shared__ float sscale[512];
    __shared__ float sshift[512];
    __shared__ float zsm[64][68];
    __shared__ float y2sm[64][33];
    __shared__ float scale2[32], shift2[32];

    int tid = threadIdx.x;

    if (tid < 512) {
        float s = 0.f, s2 = 0.f;
        for (int b = 0; b < 64; b++) {
            float v = y1raw[b * 512 + tid];
            float h = v / (1.0f + __expf(-v));
            s += h;
            s2 += h * h;
        }
        float mu = s * (1.0f / 64.0f);
        float var = s2 * (1.0f / 64.0f) - mu * mu;
        float sc = rsqrtf(var + 1e-5f) * g1[tid];
        sscale[tid] = sc;
        sshift[tid] = be1[tid] - mu * sc;
    }
    __syncthreads();

    int b0 = tid >> 5;
    int b1 = b0 + 32;
    int j2 = tid & 31;
    float acc0 = bf2[j2], acc1 = acc0;
    for (int kc = 0; kc < 8; kc++) {
        __syncthreads();
#pragma unroll
        for (int c = 0; c < 4; c++) {
            int lin = tid + c * 1024;
            int bb = lin >> 6;
            int kk = lin & 63;
            int k = kc * 64 + kk;
            float v = y1raw[bb * 512 + k];
            float h = v / (1.0f + __expf(-v));
            zsm[bb][kk] = h * sscale[k] + sshift[k];
        }
        __syncthreads();
        for (int kk = 0; kk < 64; kk += 4) {
            float w0 = wf2[(kc * 64 + kk + 0) * 32 + j2];
            float w1 = wf2[(kc * 64 + kk + 1) * 32 + j2];
            float w2 = wf2[(kc * 64 + kk + 2) * 32 + j2];
            float w3 = wf2[(kc * 64 + kk + 3) * 32 + j2];
            float4 za = *(const float4*)&zsm[b0][kk];
            float4 zb = *(const float4*)&zsm[b1][kk];
            acc0 += za.x * w0 + za.y * w1 + za.z * w2 + za.w * w3;
            acc1 += zb.x * w0 + zb.y * w1 + zb.z * w2 + zb.w * w3;
        }
    }
    y2sm[b0][j2] = acc0;
    y2sm[b1][j2] = acc1;
    __syncthreads();

    if (tid < 32) {
        float s = 0.f, s2 = 0.f;
        for (int b = 0; b < 64; b++) {
            float h = y2sm[b][tid];
            float hs = h / (1.0f + __expf(-h));
            s += hs;
            s2 += hs * hs;
        }
        float mu = s * (1.0f / 64.0f);
        float var = s2 * (1.0f / 64.0f) - mu * mu;
        float sc = rsqrtf(var + 1e-5f) * g2[tid];
        scale2[tid] = sc;
        shift2[tid] = be2[tid] - mu * sc;
    }
    __syncthreads();

    if (tid < 64) {
        float l0 = bf3[0], l1 = bf3[1];
        for (int k = 0; k < 32; k++) {
            float h = y2sm[tid][k];
            float hs = h / (1.0f + __expf(-h));
            float v = hs * scale2[k] + shift2[k];
            l0 += v * wf3[k * 2 + 0];
            l1 += v * wf3[k * 2 + 1];
        }
        float m = fmaxf(l0, l1);
        float e0 = __expf(l0 - m), e1 = __expf(l1 - m);
        float inv = 1.0f / (e0 + e1);
        out[tid * 2 + 0] = e0 * inv;
        out[tid * 2 + 1] = e1 * inv;
    }
}

// ---------------------------------------------------------------------------
extern "C" void kernel_launch(void* const* d_in, const int* in_sizes, int n_in,
                              void* d_out, int out_size, void* d_ws, size_t ws_size,
                              hipStream_t stream) {
    const float* x   = (const float*)d_in[0];
    const int*   ei  = (const int*)d_in[1];
    const float* w1  = (const float*)d_in[2];
    const float* b1  = (const float*)d_in[3];
    const float* w2  = (const float*)d_in[4];
    const float* b2  = (const float*)d_in[5];
    const float* pe  = (const float*)d_in[6];
    const float* wf1 = (const float*)d_in[7];
    const float* bf1 = (const float*)d_in[8];
    const float* g1  = (const float*)d_in[9];
    const float* be1 = (const float*)d_in[10];
    const float* wf2 = (const float*)d_in[11];
    const float* bf2 = (const float*)d_in[12];
    const float* g2  = (const float*)d_in[13];
    const float* be2 = (const float*)d_in[14];
    const float* wf3 = (const float*)d_in[15];
    const float* bf3 = (const float*)d_in[16];
    float* out = (float*)d_out;

    const int* srcp = ei;
    const int* dstp = ei + NEDGE;

    // workspace layout
    float* ws = (float*)d_ws;
    size_t off = 0;
    float* h1   = ws + off; off += (size_t)N_NODES * DH;
    float* ctxb = ws + off; off += (size_t)N_NODES * DH;
    float* feat = ws + off; off += (size_t)BG * NSNAP * 512;
    bf16_t* h2bf = (bf16_t*)(ws + off); off += (size_t)N_NODES * DH / 2;
    bf16_t* h2T  = (bf16_t*)(ws + off); off += (size_t)N_NODES * DH / 2;
    f16_t* zh    = (f16_t*)(ws + off);  off += (size_t)N_NODES * XHP / 2;
    f16_t* xh    = (f16_t*)(ws + off);  off += (size_t)N_NODES * XHP / 2;
    float* y1raw = ws + off; off += 64 * 512;
    f16_t* w1hT  = (f16_t*)(ws + off);  off += (size_t)DH * KP / 2;
    f16_t* w12hT = (f16_t*)(ws + off);  off += (size_t)DH * KP / 2;
    float* bvec  = ws + off; off += DH;
    int* bucketTail = (int*)(ws + off); off += NBUCK;
    int* cnt  = (int*)(ws + off); off += N_NODES;
    unsigned int* rec = (unsigned int*)(ws + off); off += (size_t)NBUCK * BCAP;
    unsigned short* eidx = (unsigned short*)(ws + off);

    cvt_xh<<<(N_NODES * 21 + 255) / 256, 256, 0, stream>>>(x, xh, bucketTail);
    prep_w12<<<DIN + 1, 128, 0, stream>>>(w1, w2, b1, w1hT, w12hT, bvec);
    epart<<<NEDGE / EPB, 256, 0, stream>>>(srcp, dstp, bucketTail, rec);
    ebuild<<<NBUCK, 256, 0, stream>>>(rec, bucketTail, cnt, eidx);

    gin1<<<N_NODES / 32, 512, 0, stream>>>(x, xh, cnt, eidx, w1hT, b1, h1, zh);
    gin2<<<N_NODES / 32, 512, 0, stream>>>(zh, cnt, eidx, w12hT, bvec, b2, pe, h2bf, h2T);
    attn_mfma<<<BG * 4, 512, 0, stream>>>(h2bf, h2T, ctxb);
    pooling<<<BG * NSNAP, 128, 0, stream>>>(h1, ctxb, bf1, feat, y1raw);
    mlp1_splitk<<<dim3(4, 64), 256, 0, stream>>>(feat, wf1, y1raw);
    head_tail<<<1, 1024, 0, stream>>>(y1raw, g1, be1, wf2, bf2, g2, be2, wf3, bf3, out);
}

// Round 15
// 339.520 us; speedup vs baseline: 1.1037x; 1.1037x over previous
//
#include <hip/hip_runtime.h>
#include <math.h>

#define N_NODES 64512
#define DIN 84
#define XHP 96           /* padded fp16 row: 192 B = 3 aligned cache lines */
#define KP 96            /* MFMA K padded to 96 = 3 x 32 */
#define USP 104          /* LDS us pitch (f16) -> bank-spread for b128 reads */
#define DH 128
#define NPG 1008
#define BG 64
#define NSNAP 12
#define NSEG 84
#define NEDGE (N_NODES * 16)
#define DEGCAP 64
#define NBUCK 252        /* dst>>8 buckets; 64512 = 252*256 */
#define EPB 4096         /* edges per epart block; NEDGE/EPB = 252 exactly */
#define BCAP 4608        /* per-bucket record capacity */
#define ATT_SCALE 0.08838834764831845f /* 1/sqrt(128) */

typedef __bf16 bf16_t;
typedef __bf16 bf16x8 __attribute__((ext_vector_type(8)));
typedef __bf16 bf16x4 __attribute__((ext_vector_type(4)));
typedef float f32x4 __attribute__((ext_vector_type(4)));
typedef _Float16 f16_t;
typedef _Float16 f16x4 __attribute__((ext_vector_type(4)));
typedef _Float16 f16x8 __attribute__((ext_vector_type(8)));

__device__ __forceinline__ f32x4 up4(f16x4 v) {
    return (f32x4){(float)v[0], (float)v[1], (float)v[2], (float)v[3]};
}

// ---------------------------------------------------------------------------
// cvt_xh: x -> fp16 copy into padded rows (stride 96); zero bucket tails.
// ---------------------------------------------------------------------------
__global__ __launch_bounds__(256) void cvt_xh(const float* __restrict__ x,
                                              f16_t* __restrict__ xh,
                                              int* __restrict__ bucketTail) {
    int t = blockIdx.x * 256 + threadIdx.x;
    if (t < N_NODES * 21) {
        int node = t / 21;
        int c = t - node * 21;
        f32x4 v = *(const f32x4*)(x + (size_t)node * DIN + c * 4);
        f16x4 o;
        o[0] = (f16_t)v[0]; o[1] = (f16_t)v[1];
        o[2] = (f16_t)v[2]; o[3] = (f16_t)v[3];
        *(f16x4*)(xh + (size_t)node * XHP + c * 4) = o;
    }
    if (t * 4 < NBUCK) {
        int4 z = {0, 0, 0, 0};
        *(int4*)(bucketTail + t * 4) = z;
    }
}

// ---------------------------------------------------------------------------
// epart: partition edges into 252 dst-buckets (LDS histogram, one global
// atomic per (block,bucket)). Record = (dst:u16 << 16) | src:u16.
// ---------------------------------------------------------------------------
__global__ __launch_bounds__(256) void epart(const int* __restrict__ src,
                                             const int* __restrict__ dst,
                                             int* __restrict__ bucketTail,
                                             unsigned int* __restrict__ rec) {
    __shared__ int lcnt[NBUCK];
    __shared__ int gbase[NBUCK];
    int tid = threadIdx.x;
    int e0 = blockIdx.x * EPB;
    for (int i = tid; i < NBUCK; i += 256) lcnt[i] = 0;
    __syncthreads();

    unsigned int r[16];
    unsigned short lp[16];
    unsigned short bk[16];
#pragma unroll
    for (int i = 0; i < 16; i++) {
        int e = e0 + tid + i * 256;  // coalesced
        int s = src[e], d = dst[e];
        r[i] = ((unsigned int)d << 16) | (unsigned int)s;
        int b = d >> 8;
        bk[i] = (unsigned short)b;
        lp[i] = (unsigned short)atomicAdd(&lcnt[b], 1);
    }
    __syncthreads();
    for (int i = tid; i < NBUCK; i += 256)
        gbase[i] = atomicAdd(&bucketTail[i], lcnt[i]);
    __syncthreads();
#pragma unroll
    for (int i = 0; i < 16; i++) {
        int b = bk[i];
        int g = gbase[b] + lp[i];
        if (g < BCAP) rec[(size_t)b * BCAP + g] = r[i];
    }
}

// ---------------------------------------------------------------------------
// ebuild: padded-CSR per 256-node bucket in LDS, edge lists grouped by
// src-range (src>>13) for chip-wide gather locality.
// ---------------------------------------------------------------------------
__global__ __launch_bounds__(256) void ebuild(const unsigned int* __restrict__ rec,
                                              const int* __restrict__ bucketTail,
                                              int* __restrict__ cnt,
                                              unsigned short* __restrict__ eidx) {
    __shared__ unsigned short stage[256 * 72];
    __shared__ int rb8[256 * 8];
    int tid = threadIdx.x;
    int b = blockIdx.x;
#pragma unroll
    for (int i = 0; i < 8; i++) rb8[tid + i * 256] = 0;
    __syncthreads();

    int n = min(bucketTail[b], BCAP);
    const unsigned int* rbp = rec + (size_t)b * BCAP;
    for (int i = tid; i < n; i += 256) {
        unsigned int rv = rbp[i];
        int ld = (rv >> 16) & 255;
        int rng = (rv & 0xffffu) >> 13;
        atomicAdd(&rb8[ld * 8 + rng], 1);
    }
    __syncthreads();
    {
        int s = 0;
#pragma unroll
        for (int r = 0; r < 8; r++) {
            int c = rb8[tid * 8 + r];
            rb8[tid * 8 + r] = s;
            s += c;
        }
        cnt[b * 256 + tid] = s;
    }
    __syncthreads();
    for (int i = tid; i < n; i += 256) {
        unsigned int rv = rbp[i];
        int ld = (rv >> 16) & 255;
        int rng = (rv & 0xffffu) >> 13;
        int p = atomicAdd(&rb8[ld * 8 + rng], 1);
        if (p < DEGCAP) stage[ld * 72 + p] = (unsigned short)(rv & 0xffffu);
    }
    __syncthreads();

    uint4* op = (uint4*)(eidx + (size_t)b * 256 * DEGCAP);
#pragma unroll
    for (int i = 0; i < 8; i++) {
        int ch = tid + i * 256;
        int node = ch >> 3, e0 = (ch & 7) << 3;
        op[ch] = *(const uint4*)&stage[node * 72 + e0];
    }
}

// ---------------------------------------------------------------------------
// prep: bvec = b1 @ w2 (f32); w1hT, w12hT = transposed fp16 weights
// [128 dims][96 k] (k-major per dim = MFMA B-fragment layout, zero-padded).
// ---------------------------------------------------------------------------
__global__ __launch_bounds__(128) void prep_w12(const float* __restrict__ w1,
                                                const float* __restrict__ w2,
                                                const float* __restrict__ b1,
                                                f16_t* __restrict__ w1hT,
                                                f16_t* __restrict__ w12hT,
                                                float* __restrict__ bvec) {
    __shared__ float rowv[DH];
    int r = blockIdx.x;
    int j = threadIdx.x;
    const float* srcv = (r < DIN) ? (w1 + (size_t)r * DH) : b1;
    rowv[j] = srcv[j];
    __syncthreads();
    float acc = 0.f;
#pragma unroll 4
    for (int k = 0; k < DH; k++) acc += rowv[k] * w2[k * DH + j];
    if (r < DIN) {
        w12hT[j * KP + r] = (f16_t)acc;
        w1hT[j * KP + r] = (f16_t)w1[(size_t)r * DH + j];
    } else {
        bvec[j] = acc;
        for (int k = DIN; k < KP; k++) {
            w1hT[j * KP + k] = (f16_t)0.f;
            w12hT[j * KP + k] = (f16_t)0.f;
        }
    }
}

// ---------------------------------------------------------------------------
// gin1: fused gather(fp16 x) + MFMA linear1 (16x16x32 f16, K=96).
// 512 threads / 32 nodes. Persists z as fp16 (zh).
// ---------------------------------------------------------------------------
__global__ __launch_bounds__(512) void gin1(const float* __restrict__ x,
                                            const f16_t* __restrict__ xh,
                                            const int* __restrict__ cnt,
                                            const unsigned short* __restrict__ eidx,
                                            const f16_t* __restrict__ w1hT,
                                            const float* __restrict__ b1,
                                            float* __restrict__ h1,
                                            f16_t* __restrict__ zh) {
    __shared__ f16_t us[32][USP];
    int n0 = blockIdx.x * 32;
    int tid = threadIdx.x;
    int grp = tid >> 4;
    int gl = tid & 15;
    int node = n0 + grp;
    int s = node * DEGCAP;
    int e = s + min(cnt[node], DEGCAP);
    bool has2 = gl < 5;

    const float* xn = x + (size_t)node * DIN;
    f32x4 a0 = *(const f32x4*)(xn + gl * 4);
    f32x4 a1 = has2 ? *(const f32x4*)(xn + 64 + gl * 4) : (f32x4){0.f, 0.f, 0.f, 0.f};

    int i = s;
    for (; i + 4 <= e; i += 4) {
        const f16_t* p0 = xh + (size_t)eidx[i] * XHP + gl * 4;
        const f16_t* p1 = xh + (size_t)eidx[i + 1] * XHP + gl * 4;
        const f16_t* p2 = xh + (size_t)eidx[i + 2] * XHP + gl * 4;
        const f16_t* p3 = xh + (size_t)eidx[i + 3] * XHP + gl * 4;
        a0 += up4(*(const f16x4*)p0) + up4(*(const f16x4*)p1) +
              up4(*(const f16x4*)p2) + up4(*(const f16x4*)p3);
        if (has2) {
            a1 += up4(*(const f16x4*)(p0 + 64)) + up4(*(const f16x4*)(p1 + 64)) +
                  up4(*(const f16x4*)(p2 + 64)) + up4(*(const f16x4*)(p3 + 64));
        }
    }
    for (; i < e; i++) {
        const f16_t* p0 = xh + (size_t)eidx[i] * XHP + gl * 4;
        a0 += up4(*(const f16x4*)p0);
        if (has2) a1 += up4(*(const f16x4*)(p0 + 64));
    }

    // z in fp16: persist to zh AND stage into us for the MFMA linear
    f16x4 z0;
    z0[0] = (f16_t)a0[0]; z0[1] = (f16_t)a0[1];
    z0[2] = (f16_t)a0[2]; z0[3] = (f16_t)a0[3];
    *(f16x4*)(zh + (size_t)node * XHP + gl * 4) = z0;
    *(f16x4*)&us[grp][gl * 4] = z0;
    if (has2) {
        f16x4 z1;
        z1[0] = (f16_t)a1[0]; z1[1] = (f16_t)a1[1];
        z1[2] = (f16_t)a1[2]; z1[3] = (f16_t)a1[3];
        *(f16x4*)(zh + (size_t)node * XHP + 64 + gl * 4) = z1;
        *(f16x4*)&us[grp][64 + gl * 4] = z1;
    }
    if (gl >= 5 && gl < 8) {  // zero K-padding cols 84..95
        f16x4 zz = {(f16_t)0.f, (f16_t)0.f, (f16_t)0.f, (f16_t)0.f};
        *(f16x4*)&us[grp][64 + gl * 4] = zz;
    }
    __syncthreads();

    // MFMA linear: wave wv owns dims wv*16..wv*16+15, both 16-node tiles
    int wv = tid >> 6, lane = tid & 63;
    int l15 = lane & 15, quad = lane >> 4;
    int dim = wv * 16 + l15;
    f32x4 acc[2];
    acc[0] = (f32x4){0.f, 0.f, 0.f, 0.f};
    acc[1] = (f32x4){0.f, 0.f, 0.f, 0.f};
#pragma unroll
    for (int ks = 0; ks < 3; ks++) {
        f16x8 bW = *(const f16x8*)(w1hT + (size_t)dim * KP + ks * 32 + quad * 8);
        f16x8 aU0 = *(const f16x8*)&us[l15][ks * 32 + quad * 8];
        f16x8 aU1 = *(const f16x8*)&us[16 + l15][ks * 32 + quad * 8];
        acc[0] = __builtin_amdgcn_mfma_f32_16x16x32_f16(aU0, bW, acc[0], 0, 0, 0);
        acc[1] = __builtin_amdgcn_mfma_f32_16x16x32_f16(aU1, bW, acc[1], 0, 0, 0);
    }
    float bias = b1[dim];
#pragma unroll
    for (int tm = 0; tm < 2; tm++) {
        int nb = n0 + tm * 16 + quad * 4;
#pragma unroll
        for (int r = 0; r < 4; r++)
            h1[(size_t)(nb + r) * DH + dim] = acc[tm][r] + bias;
    }
}

// ---------------------------------------------------------------------------
// gin2: gather z (fp16) + MFMA linear (W12, K=96) + deg-bias + pe.
// ---------------------------------------------------------------------------
__global__ __launch_bounds__(512) void gin2(const f16_t* __restrict__ zh,
                                            const int* __restrict__ cnt,
                                            const unsigned short* __restrict__ eidx,
                                            const f16_t* __restrict__ w12hT,
                                            const float* __restrict__ bvec,
                                            const float* __restrict__ b2,
                                            const float* __restrict__ pe,
                                            bf16_t* __restrict__ h2bf,
                                            bf16_t* __restrict__ h2T) {
    __shared__ f16_t us[32][USP];
    __shared__ float sdeg[32];
    int n0 = blockIdx.x * 32;
    int tid = threadIdx.x;
    int grp = tid >> 4;
    int gl = tid & 15;
    int node = n0 + grp;
    int dg = min(cnt[node], DEGCAP);
    int s = node * DEGCAP;
    int e = s + dg;
    bool has2 = gl < 5;
    if (gl == 0) sdeg[grp] = (float)(1 + dg);

    const f16_t* zn = zh + (size_t)node * XHP;
    f32x4 a0 = up4(*(const f16x4*)(zn + gl * 4));
    f32x4 a1 = has2 ? up4(*(const f16x4*)(zn + 64 + gl * 4)) : (f32x4){0.f, 0.f, 0.f, 0.f};

    int i = s;
    for (; i + 4 <= e; i += 4) {
        const f16_t* p0 = zh + (size_t)eidx[i] * XHP + gl * 4;
        const f16_t* p1 = zh + (size_t)eidx[i + 1] * XHP + gl * 4;
        const f16_t* p2 = zh + (size_t)eidx[i + 2] * XHP + gl * 4;
        const f16_t* p3 = zh + (size_t)eidx[i + 3] * XHP + gl * 4;
        a0 += up4(*(const f16x4*)p0) + up4(*(const f16x4*)p1) +
              up4(*(const f16x4*)p2) + up4(*(const f16x4*)p3);
        if (has2) {
            a1 += up4(*(const f16x4*)(p0 + 64)) + up4(*(const f16x4*)(p1 + 64)) +
                  up4(*(const f16x4*)(p2 + 64)) + up4(*(const f16x4*)(p3 + 64));
        }
    }
    for (; i < e; i++) {
        const f16_t* p0 = zh + (size_t)eidx[i] * XHP + gl * 4;
        a0 += up4(*(const f16x4*)p0);
        if (has2) a1 += up4(*(const f16x4*)(p0 + 64));
    }
    f16x4 u0;
    u0[0] = (f16_t)a0[0]; u0[1] = (f16_t)a0[1];
    u0[2] = (f16_t)a0[2]; u0[3] = (f16_t)a0[3];
    *(f16x4*)&us[grp][gl * 4] = u0;
    if (has2) {
        f16x4 u1;
        u1[0] = (f16_t)a1[0]; u1[1] = (f16_t)a1[1];
        u1[2] = (f16_t)a1[2]; u1[3] = (f16_t)a1[3];
        *(f16x4*)&us[grp][64 + gl * 4] = u1;
    }
    if (gl >= 5 && gl < 8) {
        f16x4 zz = {(f16_t)0.f, (f16_t)0.f, (f16_t)0.f, (f16_t)0.f};
        *(f16x4*)&us[grp][64 + gl * 4] = zz;
    }
    __syncthreads();

    int wv = tid >> 6, lane = tid & 63;
    int l15 = lane & 15, quad = lane >> 4;
    int dim = wv * 16 + l15;
    f32x4 acc[2];
    acc[0] = (f32x4){0.f, 0.f, 0.f, 0.f};
    acc[1] = (f32x4){0.f, 0.f, 0.f, 0.f};
#pragma unroll
    for (int ks = 0; ks < 3; ks++) {
        f16x8 bW = *(const f16x8*)(w12hT + (size_t)dim * KP + ks * 32 + quad * 8);
        f16x8 aU0 = *(const f16x8*)&us[l15][ks * 32 + quad * 8];
        f16x8 aU1 = *(const f16x8*)&us[16 + l15][ks * 32 + quad * 8];
        acc[0] = __builtin_amdgcn_mfma_f32_16x16x32_f16(aU0, bW, acc[0], 0, 0, 0);
        acc[1] = __builtin_amdgcn_mfma_f32_16x16x32_f16(aU1, bW, acc[1], 0, 0, 0);
    }

    float bb = b2[dim];
    float bv = bvec[dim];
#pragma unroll
    for (int tm = 0; tm < 2; tm++) {
        int nb = n0 + tm * 16 + quad * 4;  // 4-aligned; 4 | 1008 -> same graph
        int bg = nb / NPG;
        int pos = nb - bg * NPG;
        bf16x4 tv;
#pragma unroll
        for (int r = 0; r < 4; r++) {
            float v = acc[tm][r] + bb + sdeg[tm * 16 + quad * 4 + r] * bv +
                      pe[(size_t)(pos + r) * DH + dim];
            bf16_t vb = (bf16_t)v;
            h2bf[(size_t)(nb + r) * DH + dim] = vb;
            tv[r] = vb;
        }
        *(bf16x4*)(h2T + ((size_t)bg * DH + dim) * NPG + pos) = tv;
    }
}

// ---------------------------------------------------------------------------
// Flash MFMA attention: QTILE=256 (8 waves x 2 q-sets), grid 256, XCD
// swizzle, T14 reg-staging + double-buffered Ks/Kt, one barrier per tile.
// Ps wave-private (dedicated region). LDS 129024 B, 1 block/CU.
// ---------------------------------------------------------------------------
#define QTILE 256
#define KTILE 64
#define KS_PITCH 152
#define KT_PITCH 88
#define PS_PITCH 88
#define KSSZ 9728               /* elems: 64*152 */
#define KTSZ 11264              /* elems: 128*88 */
#define BUFSZ (KSSZ + KTSZ)     /* 20992 elems per buffer */
#define PS2_OFF (2 * BUFSZ)     /* 41984 elems */

__global__ __launch_bounds__(512, 1) void attn_mfma(const bf16_t* __restrict__ h2bf,
                                                    const bf16_t* __restrict__ h2T,
                                                    float* __restrict__ ctx) {
    __shared__ __align__(16) bf16_t smem[PS2_OFF + QTILE * PS_PITCH];  // 129024 B

    int tid = threadIdx.x;
    int wv = tid >> 6, lane = tid & 63;
    int l15 = lane & 15, quad = lane >> 4;
    // swizzle: idx = xcd | qt<<3 | bhi<<5 ; b = bhi*8 + xcd (grid 256)
    int idx = blockIdx.x;
    int xcd = idx & 7;
    int qt = (idx >> 3) & 3;
    int b = (idx >> 5) * 8 + xcd;
    const bf16_t* hb = h2bf + (size_t)b * NPG * DH;
    const bf16_t* hbT = h2T + (size_t)b * DH * NPG;

    // ---- Q B-fragments: wave wv owns q-rows qt*256 + wv*32 + set*16 + l15 ----
    bf16x8 bQ[2][4];
#pragma unroll
    for (int set = 0; set < 2; set++) {
        int qrow_frag = qt * QTILE + wv * 32 + set * 16 + l15;
        int qsrc = (qrow_frag < NPG) ? qrow_frag : 0;
#pragma unroll
        for (int kb = 0; kb < 4; kb++)
            bQ[set][kb] = *(const bf16x8*)(hb + (size_t)qsrc * DH + kb * 32 + quad * 8);
    }

    float m0 = -1e30f, li0 = 0.0f;
    float m1 = -1e30f, li1 = 0.0f;
    f32x4 O[2][8];
#pragma unroll
    for (int t = 0; t < 8; t++) {
        O[0][t] = (f32x4){0.f, 0.f, 0.f, 0.f};
        O[1][t] = (f32x4){0.f, 0.f, 0.f, 0.f};
    }

    // staging registers for the async split (4 x uint4 per thread)
    uint4 rK[2], rT[2];
#define LOADR(KT_)                                                              \
    {                                                                           \
        int kt_ = (KT_);                                                        \
        _Pragma("unroll")                                                       \
        for (int i = 0; i < 2; i++) {                                           \
            int c = tid + i * 512;                                              \
            int row = c >> 4, seg = c & 15;                                     \
            int key = kt_ * KTILE + row;                                        \
            uint4 v = {0u, 0u, 0u, 0u};                                         \
            if (key < NPG) v = *(const uint4*)(hb + (size_t)key * DH + seg * 8);\
            rK[i] = v;                                                          \
        }                                                                       \
        _Pragma("unroll")                                                       \
        for (int i = 0; i < 2; i++) {                                           \
            int c = tid + i * 512;                                              \
            int dim = c >> 3, kc = c & 7;                                       \
            int key0 = kt_ * KTILE + kc * 8;                                    \
            uint4 v = {0u, 0u, 0u, 0u};                                         \
            if (key0 < NPG) v = *(const uint4*)(hbT + (size_t)dim * NPG + key0);\
            rT[i] = v;                                                          \
        }                                                                       \
    }
#define DRAIN(BUFOFF_)                                                          \
    {                                                                           \
        int bo_ = (BUFOFF_);                                                    \
        _Pragma("unroll")                                                       \
        for (int i = 0; i < 2; i++) {                                           \
            int c = tid + i * 512;                                              \
            int row = c >> 4, seg = c & 15;                                     \
            *(uint4*)&smem[bo_ + row * KS_PITCH + seg * 8] = rK[i];             \
        }                                                                       \
        _Pragma("unroll")                                                       \
        for (int i = 0; i < 2; i++) {                                           \
            int c = tid + i * 512;                                              \
            int dim = c >> 3, kc = c & 7;                                       \
            *(uint4*)&smem[bo_ + KSSZ + dim * KT_PITCH + kc * 8] = rT[i];       \
        }                                                                       \
    }

    // prologue: tile 0 into buf0; issue tile 1 loads
    LOADR(0);
    DRAIN(0);
    LOADR(1);
    __syncthreads();

    for (int kt = 0; kt < 16; kt++) {
        int bo = (kt & 1) * BUFSZ;
        // drain next tile into the other buffer (overlaps compute across waves)
        if (kt < 15) DRAIN(((kt + 1) & 1) * BUFSZ);
        if (kt < 14) LOADR(kt + 2);

        // ---- S^T = K Q^T (buf[cur] Ks); each aK feeds both q-sets ----
        f32x4 S[2][4];
#pragma unroll
        for (int nt = 0; nt < 4; nt++) {
            S[0][nt] = (f32x4){0.f, 0.f, 0.f, 0.f};
            S[1][nt] = (f32x4){0.f, 0.f, 0.f, 0.f};
#pragma unroll
            for (int kb = 0; kb < 4; kb++) {
                bf16x8 aK = *(const bf16x8*)&smem[bo + (nt * 16 + l15) * KS_PITCH + kb * 32 + quad * 8];
                S[0][nt] = __builtin_amdgcn_mfma_f32_16x16x32_bf16(aK, bQ[0][kb], S[0][nt], 0, 0, 0);
                S[1][nt] = __builtin_amdgcn_mfma_f32_16x16x32_bf16(aK, bQ[1][kb], S[1][nt], 0, 0, 0);
            }
        }

        // ---- scale + mask + online softmax (both sets) ----
        float pmax0 = -1e30f, pmax1 = -1e30f;
#pragma unroll
        for (int nt = 0; nt < 4; nt++) {
            bool valid = (kt * KTILE + nt * 16) < NPG;  // 1008 = 63*16
#pragma unroll
            for (int r = 0; r < 4; r++) {
                float v0 = valid ? S[0][nt][r] * ATT_SCALE : -1e30f;
                float v1 = valid ? S[1][nt][r] * ATT_SCALE : -1e30f;
                S[0][nt][r] = v0;
                S[1][nt][r] = v1;
                pmax0 = fmaxf(pmax0, v0);
                pmax1 = fmaxf(pmax1, v1);
            }
        }
        pmax0 = fmaxf(pmax0, __shfl_xor(pmax0, 16));
        pmax0 = fmaxf(pmax0, __shfl_xor(pmax0, 32));
        pmax1 = fmaxf(pmax1, __shfl_xor(pmax1, 16));
        pmax1 = fmaxf(pmax1, __shfl_xor(pmax1, 32));
        float newm0 = fmaxf(m0, pmax0);
        float newm1 = fmaxf(m1, pmax1);

        float alpha0 = 1.0f, alpha1 = 1.0f;
        // exact defer: rescale only if some lane's running max grew
        if (!__all((newm0 == m0) && (newm1 == m1))) {
            alpha0 = __expf(m0 - newm0);
            alpha1 = __expf(m1 - newm1);
            float a00 = __shfl(alpha0, quad * 4 + 0);
            float a01 = __shfl(alpha0, quad * 4 + 1);
            float a02 = __shfl(alpha0, quad * 4 + 2);
            float a03 = __shfl(alpha0, quad * 4 + 3);
            float a10 = __shfl(alpha1, quad * 4 + 0);
            float a11 = __shfl(alpha1, quad * 4 + 1);
            float a12 = __shfl(alpha1, quad * 4 + 2);
            float a13 = __shfl(alpha1, quad * 4 + 3);
#pragma unroll
            for (int t = 0; t < 8; t++) {
                O[0][t][0] *= a00; O[0][t][1] *= a01; O[0][t][2] *= a02; O[0][t][3] *= a03;
                O[1][t][0] *= a10; O[1][t][1] *= a11; O[1][t][2] *= a12; O[1][t][3] *= a13;
            }
        }
        m0 = newm0;
        m1 = newm1;

        float psum0 = 0.f, psum1 = 0.f;
#pragma unroll
        for (int nt = 0; nt < 4; nt++) {
            bf16x4 pk0, pk1;
#pragma unroll
            for (int r = 0; r < 4; r++) {
                float p0 = __expf(S[0][nt][r] - newm0);
                float p1 = __expf(S[1][nt][r] - newm1);
                psum0 += p0;
                psum1 += p1;
                pk0[r] = (bf16_t)p0;
                pk1[r] = (bf16_t)p1;
            }
            *(bf16x4*)&smem[PS2_OFF + (wv * 32 + l15) * PS_PITCH + nt * 16 + quad * 4] = pk0;
            *(bf16x4*)&smem[PS2_OFF + (wv * 32 + 16 + l15) * PS_PITCH + nt * 16 + quad * 4] = pk1;
        }
        psum0 += __shfl_xor(psum0, 16);
        psum0 += __shfl_xor(psum0, 32);
        psum1 += __shfl_xor(psum1, 16);
        psum1 += __shfl_xor(psum1, 32);
        li0 = li0 * alpha0 + psum0;
        li1 = li1 * alpha1 + psum1;

        // ---- O += P V (Ps wave-private; buf[cur] Kt) ----
#pragma unroll
        for (int kb2 = 0; kb2 < 2; kb2++) {
            bf16x8 aP0 = *(const bf16x8*)&smem[PS2_OFF + (wv * 32 + l15) * PS_PITCH + kb2 * 32 + quad * 8];
            bf16x8 aP1 = *(const bf16x8*)&smem[PS2_OFF + (wv * 32 + 16 + l15) * PS_PITCH + kb2 * 32 + quad * 8];
#pragma unroll
            for (int t = 0; t < 8; t++) {
                bf16x8 bV = *(const bf16x8*)&smem[bo + KSSZ + (t * 16 + l15) * KT_PITCH + kb2 * 32 + quad * 8];
                O[0][t] = __builtin_amdgcn_mfma_f32_16x16x32_bf16(aP0, bV, O[0][t], 0, 0, 0);
                O[1][t] = __builtin_amdgcn_mfma_f32_16x16x32_bf16(aP1, bV, O[1][t], 0, 0, 0);
            }
        }

        __syncthreads();  // buf[cur] reads done; buf[cur^1] writes visible
    }
#undef LOADR
#undef DRAIN

    // ---- epilogue ----
    float invl0[4], invl1[4];
#pragma unroll
    for (int r = 0; r < 4; r++) {
        invl0[r] = 1.0f / __shfl(li0, quad * 4 + r);
        invl1[r] = 1.0f / __shfl(li1, quad * 4 + r);
    }
    float* cb = ctx + (size_t)b * NPG * DH;
#pragma unroll
    for (int t = 0; t < 8; t++)
#pragma unroll
        for (int r = 0; r < 4; r++) {
            int qrow0 = qt * QTILE + wv * 32 + quad * 4 + r;
            int qrow1 = qrow0 + 16;
            if (qrow0 < NPG) cb[(size_t)qrow0 * DH + t * 16 + l15] = O[0][t][r] * invl0[r];
            if (qrow1 < NPG) cb[(size_t)qrow1 * DH + t * 16 + l15] = O[1][t][r] * invl1[r];
        }
}

// ---------------------------------------------------------------------------
// pooling: segmented max/mean -> feat[B,12,512]; blocks 0..255 init y1raw
// ---------------------------------------------------------------------------
__global__ __launch_bounds__(128) void pooling(const float* __restrict__ h1,
                                               const float* __restrict__ ctx,
                                               const float* __restrict__ bf1,
                                               float* __restrict__ feat,
                                               float* __restrict__ y1raw) {
    int bs = blockIdx.x;
    int d = threadIdx.x;
    if (bs < 256) {
        int i = bs * 128 + d;
        y1raw[i] = bf1[i & 511];
    }
    int base = bs * NSEG;
    float mx1 = -1e30f, sm1 = 0.f, mx2 = -1e30f, sm2 = 0.f;
    for (int n = 0; n < NSEG; n++) {
        float v1 = h1[(size_t)(base + n) * DH + d];
        mx1 = fmaxf(mx1, v1);
        sm1 += v1;
        float v2 = ctx[(size_t)(base + n) * DH + d];
        mx2 = fmaxf(mx2, v2);
        sm2 += v2;
    }
    const float invs = 1.0f / NSEG;
    feat[bs * 512 + d] = mx1;
    feat[bs * 512 + 128 + d] = sm1 * invs;
    feat[bs * 512 + 256 + d] = mx2;
    feat[bs * 512 + 384 + d] = sm2 * invs;
}

// ---------------------------------------------------------------------------
// mlp1: split-K GEMM, fp32 atomic accumulation into bias-initialized y1raw
// ---------------------------------------------------------------------------
#define MLP1_KCH 96
__global__ __launch_bounds__(256) void mlp1_splitk(const float* __restrict__ feat,
                                                   const float* __restrict__ wf1,
                                                   float* __restrict__ y1raw) {
    __shared__ float fl[64][MLP1_KCH];
    int k0 = blockIdx.y * MLP1_KCH;
    int tid = threadIdx.x;
    for (int c = tid; c < 64 * MLP1_KCH; c += 256) {
        int row = c / MLP1_KCH;
        int kk = c - row * MLP1_KCH;
        fl[row][kk] = feat[(size_t)row * 6144 + k0 + kk];
    }
    __syncthreads();
    int col = blockIdx.x * 128 + (tid & 127);
    int rbase = (tid >> 7) * 32;
    float acc[32];
#pragma unroll
    for (int r = 0; r < 32; r++) acc[r] = 0.f;
    for (int kg = 0; kg < MLP1_KCH; kg += 4) {
        float w0 = wf1[(size_t)(k0 + kg + 0) * 512 + col];
        float w1 = wf1[(size_t)(k0 + kg + 1) * 512 + col];
        float w2 = wf1[(size_t)(k0 + kg + 2) * 512 + col];
        float w3 = wf1[(size_t)(k0 + kg + 3) * 512 + col];
#pragma unroll
        for (int r = 0; r < 32; r++) {
            float4 f = *(const float4*)&fl[rbase + r][kg];
            acc[r] += f.x * w0 + f.y * w1 + f.z * w2 + f.w * w3;
        }
    }
#pragma unroll
    for (int r = 0; r < 32; r++)
        atomicAdd(&y1raw[(size_t)(rbase + r) * 512 + col], acc[r]);
}

// ---------------------------------------------------------------------------
// bn1s: BN1 stats (grid 4 x 128): per-feature mean/var of silu(y1raw) over
// the 64-graph batch -> sscale/sshift. Coalesced; parallel across 4 CUs.
// ---------------------------------------------------------------------------
__global__ __launch_bounds__(128) void bn1s(const float* __restrict__ y1raw,
                                            const float* __restrict__ g1,
                                            const float* __restrict__ be1,
                                            float* __restrict__ sscale,
                                            float* __restrict__ sshift) {
    int f = blockIdx.x * 128 + threadIdx.x;  // 0..511
    float s = 0.f, s2 = 0.f;
#pragma unroll 8
    for (int b = 0; b < 64; b++) {
        float v = y1raw[b * 512 + f];
        float h = v / (1.0f + __expf(-v));
        s += h;
        s2 += h * h;
    }
    float mu = s * (1.0f / 64.0f);
    float var = s2 * (1.0f / 64.0f) - mu * mu;
    float sc = rsqrtf(var + 1e-5f) * g1[f];
    sscale[f] = sc;
    sshift[f] = be1[f] - mu * sc;
}

// ---------------------------------------------------------------------------
// mlp2k: one block per graph (grid 64 x 256): z = silu(y1)*sc+sh in LDS,
// then y2[b][j] = bf2[j] + sum_k z[k]*wf2[k][j] via 8-way split-K + reduce.
// ---------------------------------------------------------------------------
__global__ __launch_bounds__(256) void mlp2k(const float* __restrict__ y1raw,
                                             const float* __restrict__ sscale,
                                             const float* __restrict__ sshift,
                                             const float* __restrict__ wf2,
                                             const float* __restrict__ bf2,
                                             float* __restrict__ y2raw) {
    __shared__ float zrow[512];
    __shared__ float part[8][33];
    int b = blockIdx.x;
    int tid = threadIdx.x;
    for (int k = tid; k < 512; k += 256) {
        float v = y1raw[b * 512 + k];
        float h = v / (1.0f + __expf(-v));
        zrow[k] = h * sscale[k] + sshift[k];
    }
    __syncthreads();
    int j = tid & 31, s = tid >> 5;
    float acc = 0.f;
    int k0 = s * 64;
#pragma unroll 8
    for (int k = 0; k < 64; k++)
        acc += zrow[k0 + k] * wf2[(k0 + k) * 32 + j];
    part[s][j] = acc;
    __syncthreads();
    if (tid < 32) {
        float a = bf2[tid];
#pragma unroll
        for (int ss = 0; ss < 8; ss++) a += part[ss][tid];
        y2raw[b * 32 + tid] = a;
    }
}

// ---------------------------------------------------------------------------
// tail: BN2(silu) -> mlp3 -> softmax. One small block (the only truly
// serial part; ~2 us of work).
// ---------------------------------------------------------------------------
__global__ __launch_bounds__(256) void tail(const float* __restrict__ y2raw,
                                            const float* __restrict__ g2,
                                            const float* __restrict__ be2,
                                            const float* __restrict__ wf3,
                                            const float* __restrict__ bf3,
                                            float* __restrict__ out) {
    __shared__ float y2sm[64][33];
    __shared__ float scale2[32], shift2[32];
    int tid = threadIdx.x;
    for (int i = tid; i < 64 * 32; i += 256)
        y2sm[i >> 5][i & 31] = y2raw[i];
    __syncthreads();

    if (tid < 32) {
        float s = 0.f, s2 = 0.f;
        for (int b = 0; b < 64; b++) {
            float h = y2sm[b][tid];
            float hs = h / (1.0f + __expf(-h));
            s += hs;
            s2 += hs * hs;
        }
        float mu = s * (1.0f / 64.0f);
        float var = s2 * (1.0f / 64.0f) - mu * mu;
        float sc = rsqrtf(var + 1e-5f) * g2[tid];
        scale2[tid] = sc;
        shift2[tid] = be2[tid] - mu * sc;
    }
    __syncthreads();

    if (tid < 64) {
        float l0 = bf3[0], l1 = bf3[1];
        for (int k = 0; k < 32; k++) {
            float h = y2sm[tid][k];
            float hs = h / (1.0f + __expf(-h));
            float v = hs * scale2[k] + shift2[k];
            l0 += v * wf3[k * 2 + 0];
            l1 += v * wf3[k * 2 + 1];
        }
        float m = fmaxf(l0, l1);
        float e0 = __expf(l0 - m), e1 = __expf(l1 - m);
        float inv = 1.0f / (e0 + e1);
        out[tid * 2 + 0] = e0 * inv;
        out[tid * 2 + 1] = e1 * inv;
    }
}

// ---------------------------------------------------------------------------
extern "C" void kernel_launch(void* const* d_in, const int* in_sizes, int n_in,
                              void* d_out, int out_size, void* d_ws, size_t ws_size,
                              hipStream_t stream) {
    const float* x   = (const float*)d_in[0];
    const int*   ei  = (const int*)d_in[1];
    const float* w1  = (const float*)d_in[2];
    const float* b1  = (const float*)d_in[3];
    const float* w2  = (const float*)d_in[4];
    const float* b2  = (const float*)d_in[5];
    const float* pe  = (const float*)d_in[6];
    const float* wf1 = (const float*)d_in[7];
    const float* bf1 = (const float*)d_in[8];
    const float* g1  = (const float*)d_in[9];
    const float* be1 = (const float*)d_in[10];
    const float* wf2 = (const float*)d_in[11];
    const float* bf2 = (const float*)d_in[12];
    const float* g2  = (const float*)d_in[13];
    const float* be2 = (const float*)d_in[14];
    const float* wf3 = (const float*)d_in[15];
    const float* bf3 = (const float*)d_in[16];
    float* out = (float*)d_out;

    const int* srcp = ei;
    const int* dstp = ei + NEDGE;

    // workspace layout
    float* ws = (float*)d_ws;
    size_t off = 0;
    float* h1   = ws + off; off += (size_t)N_NODES * DH;
    float* ctxb = ws + off; off += (size_t)N_NODES * DH;
    float* feat = ws + off; off += (size_t)BG * NSNAP * 512;
    bf16_t* h2bf = (bf16_t*)(ws + off); off += (size_t)N_NODES * DH / 2;
    bf16_t* h2T  = (bf16_t*)(ws + off); off += (size_t)N_NODES * DH / 2;
    f16_t* zh    = (f16_t*)(ws + off);  off += (size_t)N_NODES * XHP / 2;
    f16_t* xh    = (f16_t*)(ws + off);  off += (size_t)N_NODES * XHP / 2;
    float* y1raw = ws + off; off += 64 * 512;
    float* sscale = ws + off; off += 512;
    float* sshift = ws + off; off += 512;
    float* y2raw  = ws + off; off += 64 * 32;
    f16_t* w1hT  = (f16_t*)(ws + off);  off += (size_t)DH * KP / 2;
    f16_t* w12hT = (f16_t*)(ws + off);  off += (size_t)DH * KP / 2;
    float* bvec  = ws + off; off += DH;
    int* bucketTail = (int*)(ws + off); off += NBUCK;
    int* cnt  = (int*)(ws + off); off += N_NODES;
    unsigned int* rec = (unsigned int*)(ws + off); off += (size_t)NBUCK * BCAP;
    unsigned short* eidx = (unsigned short*)(ws + off);

    cvt_xh<<<(N_NODES * 21 + 255) / 256, 256, 0, stream>>>(x, xh, bucketTail);
    prep_w12<<<DIN + 1, 128, 0, stream>>>(w1, w2, b1, w1hT, w12hT, bvec);
    epart<<<NEDGE / EPB, 256, 0, stream>>>(srcp, dstp, bucketTail, rec);
    ebuild<<<NBUCK, 256, 0, stream>>>(rec, bucketTail, cnt, eidx);

    gin1<<<N_NODES / 32, 512, 0, stream>>>(x, xh, cnt, eidx, w1hT, b1, h1, zh);
    gin2<<<N_NODES / 32, 512, 0, stream>>>(zh, cnt, eidx, w12hT, bvec, b2, pe, h2bf, h2T);
    attn_mfma<<<BG * 4, 512, 0, stream>>>(h2bf, h2T, ctxb);
    pooling<<<BG * NSNAP, 128, 0, stream>>>(h1, ctxb, bf1, feat, y1raw);
    mlp1_splitk<<<dim3(4, 64), 256, 0, stream>>>(feat, wf1, y1raw);
    bn1s<<<4, 128, 0, stream>>>(y1raw, g1, be1, sscale, sshift);
    mlp2k<<<64, 256, 0, stream>>>(y1raw, sscale, sshift, wf2, bf2, y2raw);
    tail<<<1, 256, 0, stream>>>(y2raw, g2, be2, wf3, bf3, out);
}

// Round 16
// 325.653 us; speedup vs baseline: 1.1507x; 1.0426x over previous
//
#include <hip/hip_runtime.h>
#include <math.h>

#define N_NODES 64512
#define DIN 84
#define XHP 96           /* padded fp16 row: 192 B = 3 aligned cache lines */
#define KP 96            /* MFMA K padded to 96 = 3 x 32 */
#define USP 104          /* LDS us pitch (f16) -> bank-spread for b128 reads */
#define DH 128
#define NPG 1008
#define BG 64
#define NSNAP 12
#define NSEG 84
#define NEDGE (N_NODES * 16)
#define DEGCAP 64
#define NBUCK 252        /* dst>>8 buckets; 64512 = 252*256 */
#define EPB 4096         /* edges per epart block; NEDGE/EPB = 252 exactly */
#define BCAP 4608        /* per-bucket record capacity */
#define ATT_SCALE 0.08838834764831845f /* 1/sqrt(128) */

typedef __bf16 bf16_t;
typedef __bf16 bf16x8 __attribute__((ext_vector_type(8)));
typedef __bf16 bf16x4 __attribute__((ext_vector_type(4)));
typedef float f32x4 __attribute__((ext_vector_type(4)));
typedef _Float16 f16_t;
typedef _Float16 f16x4 __attribute__((ext_vector_type(4)));
typedef _Float16 f16x8 __attribute__((ext_vector_type(8)));

__device__ __forceinline__ f32x4 up4(f16x4 v) {
    return (f32x4){(float)v[0], (float)v[1], (float)v[2], (float)v[3]};
}

// ---------------------------------------------------------------------------
// cvt_xh: x -> fp16 copy into padded rows (stride 96); zero bucket tails.
// ---------------------------------------------------------------------------
__global__ __launch_bounds__(256) void cvt_xh(const float* __restrict__ x,
                                              f16_t* __restrict__ xh,
                                              int* __restrict__ bucketTail) {
    int t = blockIdx.x * 256 + threadIdx.x;
    if (t < N_NODES * 21) {
        int node = t / 21;
        int c = t - node * 21;
        f32x4 v = *(const f32x4*)(x + (size_t)node * DIN + c * 4);
        f16x4 o;
        o[0] = (f16_t)v[0]; o[1] = (f16_t)v[1];
        o[2] = (f16_t)v[2]; o[3] = (f16_t)v[3];
        *(f16x4*)(xh + (size_t)node * XHP + c * 4) = o;
    }
    if (t * 4 < NBUCK) {
        int4 z = {0, 0, 0, 0};
        *(int4*)(bucketTail + t * 4) = z;
    }
}

// ---------------------------------------------------------------------------
// epart: partition edges into 252 dst-buckets (LDS histogram, one global
// atomic per (block,bucket)). Record = (dst:u16 << 16) | src:u16.
// ---------------------------------------------------------------------------
__global__ __launch_bounds__(256) void epart(const int* __restrict__ src,
                                             const int* __restrict__ dst,
                                             int* __restrict__ bucketTail,
                                             unsigned int* __restrict__ rec) {
    __shared__ int lcnt[NBUCK];
    __shared__ int gbase[NBUCK];
    int tid = threadIdx.x;
    int e0 = blockIdx.x * EPB;
    for (int i = tid; i < NBUCK; i += 256) lcnt[i] = 0;
    __syncthreads();

    unsigned int r[16];
    unsigned short lp[16];
    unsigned short bk[16];
#pragma unroll
    for (int i = 0; i < 16; i++) {
        int e = e0 + tid + i * 256;  // coalesced
        int s = src[e], d = dst[e];
        r[i] = ((unsigned int)d << 16) | (unsigned int)s;
        int b = d >> 8;
        bk[i] = (unsigned short)b;
        lp[i] = (unsigned short)atomicAdd(&lcnt[b], 1);
    }
    __syncthreads();
    for (int i = tid; i < NBUCK; i += 256)
        gbase[i] = atomicAdd(&bucketTail[i], lcnt[i]);
    __syncthreads();
#pragma unroll
    for (int i = 0; i < 16; i++) {
        int b = bk[i];
        int g = gbase[b] + lp[i];
        if (g < BCAP) rec[(size_t)b * BCAP + g] = r[i];
    }
}

// ---------------------------------------------------------------------------
// ebuild: padded-CSR per 256-node bucket in LDS, edge lists grouped by
// src-range (src>>13) for chip-wide gather locality.
// ---------------------------------------------------------------------------
__global__ __launch_bounds__(256) void ebuild(const unsigned int* __restrict__ rec,
                                              const int* __restrict__ bucketTail,
                                              int* __restrict__ cnt,
                                              unsigned short* __restrict__ eidx) {
    __shared__ unsigned short stage[256 * 72];
    __shared__ int rb8[256 * 8];
    int tid = threadIdx.x;
    int b = blockIdx.x;
#pragma unroll
    for (int i = 0; i < 8; i++) rb8[tid + i * 256] = 0;
    __syncthreads();

    int n = min(bucketTail[b], BCAP);
    const unsigned int* rbp = rec + (size_t)b * BCAP;
    for (int i = tid; i < n; i += 256) {
        unsigned int rv = rbp[i];
        int ld = (rv >> 16) & 255;
        int rng = (rv & 0xffffu) >> 13;
        atomicAdd(&rb8[ld * 8 + rng], 1);
    }
    __syncthreads();
    {
        int s = 0;
#pragma unroll
        for (int r = 0; r < 8; r++) {
            int c = rb8[tid * 8 + r];
            rb8[tid * 8 + r] = s;
            s += c;
        }
        cnt[b * 256 + tid] = s;
    }
    __syncthreads();
    for (int i = tid; i < n; i += 256) {
        unsigned int rv = rbp[i];
        int ld = (rv >> 16) & 255;
        int rng = (rv & 0xffffu) >> 13;
        int p = atomicAdd(&rb8[ld * 8 + rng], 1);
        if (p < DEGCAP) stage[ld * 72 + p] = (unsigned short)(rv & 0xffffu);
    }
    __syncthreads();

    uint4* op = (uint4*)(eidx + (size_t)b * 256 * DEGCAP);
#pragma unroll
    for (int i = 0; i < 8; i++) {
        int ch = tid + i * 256;
        int node = ch >> 3, e0 = (ch & 7) << 3;
        op[ch] = *(const uint4*)&stage[node * 72 + e0];
    }
}

// ---------------------------------------------------------------------------
// prep: bvec = b1 @ w2 (f32); w1hT, w12hT = transposed fp16 weights
// [128 dims][96 k] (k-major per dim = MFMA B-fragment layout, zero-padded).
// ---------------------------------------------------------------------------
__global__ __launch_bounds__(128) void prep_w12(const float* __restrict__ w1,
                                                const float* __restrict__ w2,
                                                const float* __restrict__ b1,
                                                f16_t* __restrict__ w1hT,
                                                f16_t* __restrict__ w12hT,
                                                float* __restrict__ bvec) {
    __shared__ float rowv[DH];
    int r = blockIdx.x;
    int j = threadIdx.x;
    const float* srcv = (r < DIN) ? (w1 + (size_t)r * DH) : b1;
    rowv[j] = srcv[j];
    __syncthreads();
    float acc = 0.f;
#pragma unroll 4
    for (int k = 0; k < DH; k++) acc += rowv[k] * w2[k * DH + j];
    if (r < DIN) {
        w12hT[j * KP + r] = (f16_t)acc;
        w1hT[j * KP + r] = (f16_t)w1[(size_t)r * DH + j];
    } else {
        bvec[j] = acc;
        for (int k = DIN; k < KP; k++) {
            w1hT[j * KP + k] = (f16_t)0.f;
            w12hT[j * KP + k] = (f16_t)0.f;
        }
    }
}

// ---------------------------------------------------------------------------
// gin1: fused gather(fp16 x) + MFMA linear1 (16x16x32 f16, K=96).
// 512 threads / 32 nodes. Self-term from xh (fp16). h1 emitted as fp16
// (only consumer is pooling max/mean). Persists z as fp16 (zh).
// ---------------------------------------------------------------------------
__global__ __launch_bounds__(512) void gin1(const f16_t* __restrict__ xh,
                                            const int* __restrict__ cnt,
                                            const unsigned short* __restrict__ eidx,
                                            const f16_t* __restrict__ w1hT,
                                            const float* __restrict__ b1,
                                            f16_t* __restrict__ h1h,
                                            f16_t* __restrict__ zh) {
    __shared__ f16_t us[32][USP];
    int n0 = blockIdx.x * 32;
    int tid = threadIdx.x;
    int grp = tid >> 4;
    int gl = tid & 15;
    int node = n0 + grp;
    int s = node * DEGCAP;
    int e = s + min(cnt[node], DEGCAP);
    bool has2 = gl < 5;

    const f16_t* xn = xh + (size_t)node * XHP;
    f32x4 a0 = up4(*(const f16x4*)(xn + gl * 4));
    f32x4 a1 = has2 ? up4(*(const f16x4*)(xn + 64 + gl * 4)) : (f32x4){0.f, 0.f, 0.f, 0.f};

    int i = s;
    for (; i + 4 <= e; i += 4) {
        const f16_t* p0 = xh + (size_t)eidx[i] * XHP + gl * 4;
        const f16_t* p1 = xh + (size_t)eidx[i + 1] * XHP + gl * 4;
        const f16_t* p2 = xh + (size_t)eidx[i + 2] * XHP + gl * 4;
        const f16_t* p3 = xh + (size_t)eidx[i + 3] * XHP + gl * 4;
        a0 += up4(*(const f16x4*)p0) + up4(*(const f16x4*)p1) +
              up4(*(const f16x4*)p2) + up4(*(const f16x4*)p3);
        if (has2) {
            a1 += up4(*(const f16x4*)(p0 + 64)) + up4(*(const f16x4*)(p1 + 64)) +
                  up4(*(const f16x4*)(p2 + 64)) + up4(*(const f16x4*)(p3 + 64));
        }
    }
    for (; i < e; i++) {
        const f16_t* p0 = xh + (size_t)eidx[i] * XHP + gl * 4;
        a0 += up4(*(const f16x4*)p0);
        if (has2) a1 += up4(*(const f16x4*)(p0 + 64));
    }

    // z in fp16: persist to zh AND stage into us for the MFMA linear
    f16x4 z0;
    z0[0] = (f16_t)a0[0]; z0[1] = (f16_t)a0[1];
    z0[2] = (f16_t)a0[2]; z0[3] = (f16_t)a0[3];
    *(f16x4*)(zh + (size_t)node * XHP + gl * 4) = z0;
    *(f16x4*)&us[grp][gl * 4] = z0;
    if (has2) {
        f16x4 z1;
        z1[0] = (f16_t)a1[0]; z1[1] = (f16_t)a1[1];
        z1[2] = (f16_t)a1[2]; z1[3] = (f16_t)a1[3];
        *(f16x4*)(zh + (size_t)node * XHP + 64 + gl * 4) = z1;
        *(f16x4*)&us[grp][64 + gl * 4] = z1;
    }
    if (gl >= 5 && gl < 8) {  // zero K-padding cols 84..95
        f16x4 zz = {(f16_t)0.f, (f16_t)0.f, (f16_t)0.f, (f16_t)0.f};
        *(f16x4*)&us[grp][64 + gl * 4] = zz;
    }
    __syncthreads();

    // MFMA linear: wave wv owns dims wv*16..wv*16+15, both 16-node tiles
    int wv = tid >> 6, lane = tid & 63;
    int l15 = lane & 15, quad = lane >> 4;
    int dim = wv * 16 + l15;
    f32x4 acc[2];
    acc[0] = (f32x4){0.f, 0.f, 0.f, 0.f};
    acc[1] = (f32x4){0.f, 0.f, 0.f, 0.f};
#pragma unroll
    for (int ks = 0; ks < 3; ks++) {
        f16x8 bW = *(const f16x8*)(w1hT + (size_t)dim * KP + ks * 32 + quad * 8);
        f16x8 aU0 = *(const f16x8*)&us[l15][ks * 32 + quad * 8];
        f16x8 aU1 = *(const f16x8*)&us[16 + l15][ks * 32 + quad * 8];
        acc[0] = __builtin_amdgcn_mfma_f32_16x16x32_f16(aU0, bW, acc[0], 0, 0, 0);
        acc[1] = __builtin_amdgcn_mfma_f32_16x16x32_f16(aU1, bW, acc[1], 0, 0, 0);
    }
    float bias = b1[dim];
#pragma unroll
    for (int tm = 0; tm < 2; tm++) {
        int nb = n0 + tm * 16 + quad * 4;
#pragma unroll
        for (int r = 0; r < 4; r++)
            h1h[(size_t)(nb + r) * DH + dim] = (f16_t)(acc[tm][r] + bias);
    }
}

// ---------------------------------------------------------------------------
// gin2: gather z (fp16) + MFMA linear (W12, K=96) + deg-bias + pe.
// ---------------------------------------------------------------------------
__global__ __launch_bounds__(512) void gin2(const f16_t* __restrict__ zh,
                                            const int* __restrict__ cnt,
                                            const unsigned short* __restrict__ eidx,
                                            const f16_t* __restrict__ w12hT,
                                            const float* __restrict__ bvec,
                                            const float* __restrict__ b2,
                                            const float* __restrict__ pe,
                                            bf16_t* __restrict__ h2bf,
                                            bf16_t* __restrict__ h2T) {
    __shared__ f16_t us[32][USP];
    __shared__ float sdeg[32];
    int n0 = blockIdx.x * 32;
    int tid = threadIdx.x;
    int grp = tid >> 4;
    int gl = tid & 15;
    int node = n0 + grp;
    int dg = min(cnt[node], DEGCAP);
    int s = node * DEGCAP;
    int e = s + dg;
    bool has2 = gl < 5;
    if (gl == 0) sdeg[grp] = (float)(1 + dg);

    const f16_t* zn = zh + (size_t)node * XHP;
    f32x4 a0 = up4(*(const f16x4*)(zn + gl * 4));
    f32x4 a1 = has2 ? up4(*(const f16x4*)(zn + 64 + gl * 4)) : (f32x4){0.f, 0.f, 0.f, 0.f};

    int i = s;
    for (; i + 4 <= e; i += 4) {
        const f16_t* p0 = zh + (size_t)eidx[i] * XHP + gl * 4;
        const f16_t* p1 = zh + (size_t)eidx[i + 1] * XHP + gl * 4;
        const f16_t* p2 = zh + (size_t)eidx[i + 2] * XHP + gl * 4;
        const f16_t* p3 = zh + (size_t)eidx[i + 3] * XHP + gl * 4;
        a0 += up4(*(const f16x4*)p0) + up4(*(const f16x4*)p1) +
              up4(*(const f16x4*)p2) + up4(*(const f16x4*)p3);
        if (has2) {
            a1 += up4(*(const f16x4*)(p0 + 64)) + up4(*(const f16x4*)(p1 + 64)) +
                  up4(*(const f16x4*)(p2 + 64)) + up4(*(const f16x4*)(p3 + 64));
        }
    }
    for (; i < e; i++) {
        const f16_t* p0 = zh + (size_t)eidx[i] * XHP + gl * 4;
        a0 += up4(*(const f16x4*)p0);
        if (has2) a1 += up4(*(const f16x4*)(p0 + 64));
    }
    f16x4 u0;
    u0[0] = (f16_t)a0[0]; u0[1] = (f16_t)a0[1];
    u0[2] = (f16_t)a0[2]; u0[3] = (f16_t)a0[3];
    *(f16x4*)&us[grp][gl * 4] = u0;
    if (has2) {
        f16x4 u1;
        u1[0] = (f16_t)a1[0]; u1[1] = (f16_t)a1[1];
        u1[2] = (f16_t)a1[2]; u1[3] = (f16_t)a1[3];
        *(f16x4*)&us[grp][64 + gl * 4] = u1;
    }
    if (gl >= 5 && gl < 8) {
        f16x4 zz = {(f16_t)0.f, (f16_t)0.f, (f16_t)0.f, (f16_t)0.f};
        *(f16x4*)&us[grp][64 + gl * 4] = zz;
    }
    __syncthreads();

    int wv = tid >> 6, lane = tid & 63;
    int l15 = lane & 15, quad = lane >> 4;
    int dim = wv * 16 + l15;
    f32x4 acc[2];
    acc[0] = (f32x4){0.f, 0.f, 0.f, 0.f};
    acc[1] = (f32x4){0.f, 0.f, 0.f, 0.f};
#pragma unroll
    for (int ks = 0; ks < 3; ks++) {
        f16x8 bW = *(const f16x8*)(w12hT + (size_t)dim * KP + ks * 32 + quad * 8);
        f16x8 aU0 = *(const f16x8*)&us[l15][ks * 32 + quad * 8];
        f16x8 aU1 = *(const f16x8*)&us[16 + l15][ks * 32 + quad * 8];
        acc[0] = __builtin_amdgcn_mfma_f32_16x16x32_f16(aU0, bW, acc[0], 0, 0, 0);
        acc[1] = __builtin_amdgcn_mfma_f32_16x16x32_f16(aU1, bW, acc[1], 0, 0, 0);
    }

    float bb = b2[dim];
    float bv = bvec[dim];
#pragma unroll
    for (int tm = 0; tm < 2; tm++) {
        int nb = n0 + tm * 16 + quad * 4;  // 4-aligned; 4 | 1008 -> same graph
        int bg = nb / NPG;
        int pos = nb - bg * NPG;
        bf16x4 tv;
#pragma unroll
        for (int r = 0; r < 4; r++) {
            float v = acc[tm][r] + bb + sdeg[tm * 16 + quad * 4 + r] * bv +
                      pe[(size_t)(pos + r) * DH + dim];
            bf16_t vb = (bf16_t)v;
            h2bf[(size_t)(nb + r) * DH + dim] = vb;
            tv[r] = vb;
        }
        *(bf16x4*)(h2T + ((size_t)bg * DH + dim) * NPG + pos) = tv;
    }
}

// ---------------------------------------------------------------------------
// Flash MFMA attention: QTILE=256 (8 waves x 2 q-sets), grid 256, XCD
// swizzle, T14 reg-staging + double-buffered Ks/Kt, one barrier per tile.
// Ps wave-private. ctx emitted as fp16 (only consumer is pooling).
// LDS 129024 B, 1 block/CU.
// ---------------------------------------------------------------------------
#define QTILE 256
#define KTILE 64
#define KS_PITCH 152
#define KT_PITCH 88
#define PS_PITCH 88
#define KSSZ 9728               /* elems: 64*152 */
#define KTSZ 11264              /* elems: 128*88 */
#define BUFSZ (KSSZ + KTSZ)     /* 20992 elems per buffer */
#define PS2_OFF (2 * BUFSZ)     /* 41984 elems */

__global__ __launch_bounds__(512, 1) void attn_mfma(const bf16_t* __restrict__ h2bf,
                                                    const bf16_t* __restrict__ h2T,
                                                    f16_t* __restrict__ ctxh) {
    __shared__ __align__(16) bf16_t smem[PS2_OFF + QTILE * PS_PITCH];  // 129024 B

    int tid = threadIdx.x;
    int wv = tid >> 6, lane = tid & 63;
    int l15 = lane & 15, quad = lane >> 4;
    // swizzle: idx = xcd | qt<<3 | bhi<<5 ; b = bhi*8 + xcd (grid 256)
    int idx = blockIdx.x;
    int xcd = idx & 7;
    int qt = (idx >> 3) & 3;
    int b = (idx >> 5) * 8 + xcd;
    const bf16_t* hb = h2bf + (size_t)b * NPG * DH;
    const bf16_t* hbT = h2T + (size_t)b * DH * NPG;

    // ---- Q B-fragments: wave wv owns q-rows qt*256 + wv*32 + set*16 + l15 ----
    bf16x8 bQ[2][4];
#pragma unroll
    for (int set = 0; set < 2; set++) {
        int qrow_frag = qt * QTILE + wv * 32 + set * 16 + l15;
        int qsrc = (qrow_frag < NPG) ? qrow_frag : 0;
#pragma unroll
        for (int kb = 0; kb < 4; kb++)
            bQ[set][kb] = *(const bf16x8*)(hb + (size_t)qsrc * DH + kb * 32 + quad * 8);
    }

    float m0 = -1e30f, li0 = 0.0f;
    float m1 = -1e30f, li1 = 0.0f;
    f32x4 O[2][8];
#pragma unroll
    for (int t = 0; t < 8; t++) {
        O[0][t] = (f32x4){0.f, 0.f, 0.f, 0.f};
        O[1][t] = (f32x4){0.f, 0.f, 0.f, 0.f};
    }

    // staging registers for the async split (4 x uint4 per thread)
    uint4 rK[2], rT[2];
#define LOADR(KT_)                                                              \
    {                                                                           \
        int kt_ = (KT_);                                                        \
        _Pragma("unroll")                                                       \
        for (int i = 0; i < 2; i++) {                                           \
            int c = tid + i * 512;                                              \
            int row = c >> 4, seg = c & 15;                                     \
            int key = kt_ * KTILE + row;                                        \
            uint4 v = {0u, 0u, 0u, 0u};                                         \
            if (key < NPG) v = *(const uint4*)(hb + (size_t)key * DH + seg * 8);\
            rK[i] = v;                                                          \
        }                                                                       \
        _Pragma("unroll")                                                       \
        for (int i = 0; i < 2; i++) {                                           \
            int c = tid + i * 512;                                              \
            int dim = c >> 3, kc = c & 7;                                       \
            int key0 = kt_ * KTILE + kc * 8;                                    \
            uint4 v = {0u, 0u, 0u, 0u};                                         \
            if (key0 < NPG) v = *(const uint4*)(hbT + (size_t)dim * NPG + key0);\
            rT[i] = v;                                                          \
        }                                                                       \
    }
#define DRAIN(BUFOFF_)                                                          \
    {                                                                           \
        int bo_ = (BUFOFF_);                                                    \
        _Pragma("unroll")                                                       \
        for (int i = 0; i < 2; i++) {                                           \
            int c = tid + i * 512;                                              \
            int row = c >> 4, seg = c & 15;                                     \
            *(uint4*)&smem[bo_ + row * KS_PITCH + seg * 8] = rK[i];             \
        }                                                                       \
        _Pragma("unroll")                                                       \
        for (int i = 0; i < 2; i++) {                                           \
            int c = tid + i * 512;                                              \
            int dim = c >> 3, kc = c & 7;                                       \
            *(uint4*)&smem[bo_ + KSSZ + dim * KT_PITCH + kc * 8] = rT[i];       \
        }                                                                       \
    }

    // prologue: tile 0 into buf0; issue tile 1 loads
    LOADR(0);
    DRAIN(0);
    LOADR(1);
    __syncthreads();

    for (int kt = 0; kt < 16; kt++) {
        int bo = (kt & 1) * BUFSZ;
        // drain next tile into the other buffer (overlaps compute across waves)
        if (kt < 15) DRAIN(((kt + 1) & 1) * BUFSZ);
        if (kt < 14) LOADR(kt + 2);

        // ---- S^T = K Q^T (buf[cur] Ks); each aK feeds both q-sets ----
        f32x4 S[2][4];
#pragma unroll
        for (int nt = 0; nt < 4; nt++) {
            S[0][nt] = (f32x4){0.f, 0.f, 0.f, 0.f};
            S[1][nt] = (f32x4){0.f, 0.f, 0.f, 0.f};
#pragma unroll
            for (int kb = 0; kb < 4; kb++) {
                bf16x8 aK = *(const bf16x8*)&smem[bo + (nt * 16 + l15) * KS_PITCH + kb * 32 + quad * 8];
                S[0][nt] = __builtin_amdgcn_mfma_f32_16x16x32_bf16(aK, bQ[0][kb], S[0][nt], 0, 0, 0);
                S[1][nt] = __builtin_amdgcn_mfma_f32_16x16x32_bf16(aK, bQ[1][kb], S[1][nt], 0, 0, 0);
            }
        }

        // ---- scale + mask + online softmax (both sets) ----
        float pmax0 = -1e30f, pmax1 = -1e30f;
#pragma unroll
        for (int nt = 0; nt < 4; nt++) {
            bool valid = (kt * KTILE + nt * 16) < NPG;  // 1008 = 63*16
#pragma unroll
            for (int r = 0; r < 4; r++) {
                float v0 = valid ? S[0][nt][r] * ATT_SCALE : -1e30f;
                float v1 = valid ? S[1][nt][r] * ATT_SCALE : -1e30f;
                S[0][nt][r] = v0;
                S[1][nt][r] = v1;
                pmax0 = fmaxf(pmax0, v0);
                pmax1 = fmaxf(pmax1, v1);
            }
        }
        pmax0 = fmaxf(pmax0, __shfl_xor(pmax0, 16));
        pmax0 = fmaxf(pmax0, __shfl_xor(pmax0, 32));
        pmax1 = fmaxf(pmax1, __shfl_xor(pmax1, 16));
        pmax1 = fmaxf(pmax1, __shfl_xor(pmax1, 32));
        float newm0 = fmaxf(m0, pmax0);
        float newm1 = fmaxf(m1, pmax1);

        float alpha0 = 1.0f, alpha1 = 1.0f;
        // exact defer: rescale only if some lane's running max grew
        if (!__all((newm0 == m0) && (newm1 == m1))) {
            alpha0 = __expf(m0 - newm0);
            alpha1 = __expf(m1 - newm1);
            float a00 = __shfl(alpha0, quad * 4 + 0);
            float a01 = __shfl(alpha0, quad * 4 + 1);
            float a02 = __shfl(alpha0, quad * 4 + 2);
            float a03 = __shfl(alpha0, quad * 4 + 3);
            float a10 = __shfl(alpha1, quad * 4 + 0);
            float a11 = __shfl(alpha1, quad * 4 + 1);
            float a12 = __shfl(alpha1, quad * 4 + 2);
            float a13 = __shfl(alpha1, quad * 4 + 3);
#pragma unroll
            for (int t = 0; t < 8; t++) {
                O[0][t][0] *= a00; O[0][t][1] *= a01; O[0][t][2] *= a02; O[0][t][3] *= a03;
                O[1][t][0] *= a10; O[1][t][1] *= a11; O[1][t][2] *= a12; O[1][t][3] *= a13;
            }
        }
        m0 = newm0;
        m1 = newm1;

        float psum0 = 0.f, psum1 = 0.f;
#pragma unroll
        for (int nt = 0; nt < 4; nt++) {
            bf16x4 pk0, pk1;
#pragma unroll
            for (int r = 0; r < 4; r++) {
                float p0 = __expf(S[0][nt][r] - newm0);
                float p1 = __expf(S[1][nt][r] - newm1);
                psum0 += p0;
                psum1 += p1;
                pk0[r] = (bf16_t)p0;
                pk1[r] = (bf16_t)p1;
            }
            *(bf16x4*)&smem[PS2_OFF + (wv * 32 + l15) * PS_PITCH + nt * 16 + quad * 4] = pk0;
            *(bf16x4*)&smem[PS2_OFF + (wv * 32 + 16 + l15) * PS_PITCH + nt * 16 + quad * 4] = pk1;
        }
        psum0 += __shfl_xor(psum0, 16);
        psum0 += __shfl_xor(psum0, 32);
        psum1 += __shfl_xor(psum1, 16);
        psum1 += __shfl_xor(psum1, 32);
        li0 = li0 * alpha0 + psum0;
        li1 = li1 * alpha1 + psum1;

        // ---- O += P V (Ps wave-private; buf[cur] Kt) ----
#pragma unroll
        for (int kb2 = 0; kb2 < 2; kb2++) {
            bf16x8 aP0 = *(const bf16x8*)&smem[PS2_OFF + (wv * 32 + l15) * PS_PITCH + kb2 * 32 + quad * 8];
            bf16x8 aP1 = *(const bf16x8*)&smem[PS2_OFF + (wv * 32 + 16 + l15) * PS_PITCH + kb2 * 32 + quad * 8];
#pragma unroll
            for (int t = 0; t < 8; t++) {
                bf16x8 bV = *(const bf16x8*)&smem[bo + KSSZ + (t * 16 + l15) * KT_PITCH + kb2 * 32 + quad * 8];
                O[0][t] = __builtin_amdgcn_mfma_f32_16x16x32_bf16(aP0, bV, O[0][t], 0, 0, 0);
                O[1][t] = __builtin_amdgcn_mfma_f32_16x16x32_bf16(aP1, bV, O[1][t], 0, 0, 0);
            }
        }

        __syncthreads();  // buf[cur] reads done; buf[cur^1] writes visible
    }
#undef LOADR
#undef DRAIN

    // ---- epilogue (fp16 ctx) ----
    float invl0[4], invl1[4];
#pragma unroll
    for (int r = 0; r < 4; r++) {
        invl0[r] = 1.0f / __shfl(li0, quad * 4 + r);
        invl1[r] = 1.0f / __shfl(li1, quad * 4 + r);
    }
    f16_t* cb = ctxh + (size_t)b * NPG * DH;
#pragma unroll
    for (int t = 0; t < 8; t++)
#pragma unroll
        for (int r = 0; r < 4; r++) {
            int qrow0 = qt * QTILE + wv * 32 + quad * 4 + r;
            int qrow1 = qrow0 + 16;
            if (qrow0 < NPG) cb[(size_t)qrow0 * DH + t * 16 + l15] = (f16_t)(O[0][t][r] * invl0[r]);
            if (qrow1 < NPG) cb[(size_t)qrow1 * DH + t * 16 + l15] = (f16_t)(O[1][t][r] * invl1[r]);
        }
}

// ---------------------------------------------------------------------------
// pooling: segmented max/mean over fp16 h1/ctx -> feat[B,12,512];
// blocks 0..255 init y1raw
// ---------------------------------------------------------------------------
__global__ __launch_bounds__(128) void pooling(const f16_t* __restrict__ h1h,
                                               const f16_t* __restrict__ ctxh,
                                               const float* __restrict__ bf1,
                                               float* __restrict__ feat,
                                               float* __restrict__ y1raw) {
    int bs = blockIdx.x;
    int d = threadIdx.x;
    if (bs < 256) {
        int i = bs * 128 + d;
        y1raw[i] = bf1[i & 511];
    }
    int base = bs * NSEG;
    float mx1 = -1e30f, sm1 = 0.f, mx2 = -1e30f, sm2 = 0.f;
    for (int n = 0; n < NSEG; n++) {
        float v1 = (float)h1h[(size_t)(base + n) * DH + d];
        mx1 = fmaxf(mx1, v1);
        sm1 += v1;
        float v2 = (float)ctxh[(size_t)(base + n) * DH + d];
        mx2 = fmaxf(mx2, v2);
        sm2 += v2;
    }
    const float invs = 1.0f / NSEG;
    feat[bs * 512 + d] = mx1;
    feat[bs * 512 + 128 + d] = sm1 * invs;
    feat[bs * 512 + 256 + d] = mx2;
    feat[bs * 512 + 384 + d] = sm2 * invs;
}

// ---------------------------------------------------------------------------
// mlp1: split-K GEMM, fp32 atomic accumulation into bias-initialized y1raw
// ---------------------------------------------------------------------------
#define MLP1_KCH 96
__global__ __launch_bounds__(256) void mlp1_splitk(const float* __restrict__ feat,
                                                   const float* __restrict__ wf1,
                                                   float* __restrict__ y1raw) {
    __shared__ float fl[64][MLP1_KCH];
    int k0 = blockIdx.y * MLP1_KCH;
    int tid = threadIdx.x;
    for (int c = tid; c < 64 * MLP1_KCH; c += 256) {
        int row = c / MLP1_KCH;
        int kk = c - row * MLP1_KCH;
        fl[row][kk] = feat[(size_t)row * 6144 + k0 + kk];
    }
    __syncthreads();
    int col = blockIdx.x * 128 + (tid & 127);
    int rbase = (tid >> 7) * 32;
    float acc[32];
#pragma unroll
    for (int r = 0; r < 32; r++) acc[r] = 0.f;
    for (int kg = 0; kg < MLP1_KCH; kg += 4) {
        float w0 = wf1[(size_t)(k0 + kg + 0) * 512 + col];
        float w1 = wf1[(size_t)(k0 + kg + 1) * 512 + col];
        float w2 = wf1[(size_t)(k0 + kg + 2) * 512 + col];
        float w3 = wf1[(size_t)(k0 + kg + 3) * 512 + col];
#pragma unroll
        for (int r = 0; r < 32; r++) {
            float4 f = *(const float4*)&fl[rbase + r][kg];
            acc[r] += f.x * w0 + f.y * w1 + f.z * w2 + f.w * w3;
        }
    }
#pragma unroll
    for (int r = 0; r < 32; r++)
        atomicAdd(&y1raw[(size_t)(rbase + r) * 512 + col], acc[r]);
}

// ---------------------------------------------------------------------------
// bn1s: BN1 stats (grid 4 x 128): per-feature mean/var of silu(y1raw) over
// the 64-graph batch -> sscale/sshift.
// ---------------------------------------------------------------------------
__global__ __launch_bounds__(128) void bn1s(const float* __restrict__ y1raw,
                                            const float* __restrict__ g1,
                                            const float* __restrict__ be1,
                                            float* __restrict__ sscale,
                                            float* __restrict__ sshift) {
    int f = blockIdx.x * 128 + threadIdx.x;  // 0..511
    float s = 0.f, s2 = 0.f;
#pragma unroll 8
    for (int b = 0; b < 64; b++) {
        float v = y1raw[b * 512 + f];
        float h = v / (1.0f + __expf(-v));
        s += h;
        s2 += h * h;
    }
    float mu = s * (1.0f / 64.0f);
    float var = s2 * (1.0f / 64.0f) - mu * mu;
    float sc = rsqrtf(var + 1e-5f) * g1[f];
    sscale[f] = sc;
    sshift[f] = be1[f] - mu * sc;
}

// ---------------------------------------------------------------------------
// mlp2k: one block per graph (grid 64 x 256): z = silu(y1)*sc+sh in LDS,
// then y2[b][j] = bf2[j] + sum_k z[k]*wf2[k][j] via 8-way split-K + reduce.
// ---------------------------------------------------------------------------
__global__ __launch_bounds__(256) void mlp2k(const float* __restrict__ y1raw,
                                             const float* __restrict__ sscale,
                                             const float* __restrict__ sshift,
                                             const float* __restrict__ wf2,
                                             const float* __restrict__ bf2,
                                             float* __restrict__ y2raw) {
    __shared__ float zrow[512];
    __shared__ float part[8][33];
    int b = blockIdx.x;
    int tid = threadIdx.x;
    for (int k = tid; k < 512; k += 256) {
        float v = y1raw[b * 512 + k];
        float h = v / (1.0f + __expf(-v));
        zrow[k] = h * sscale[k] + sshift[k];
    }
    __syncthreads();
    int j = tid & 31, s = tid >> 5;
    float acc = 0.f;
    int k0 = s * 64;
#pragma unroll 8
    for (int k = 0; k < 64; k++)
        acc += zrow[k0 + k] * wf2[(k0 + k) * 32 + j];
    part[s][j] = acc;
    __syncthreads();
    if (tid < 32) {
        float a = bf2[tid];
#pragma unroll
        for (int ss = 0; ss < 8; ss++) a += part[ss][tid];
        y2raw[b * 32 + tid] = a;
    }
}

// ---------------------------------------------------------------------------
// tail: BN2(silu) -> mlp3 -> softmax. One small block.
// ---------------------------------------------------------------------------
__global__ __launch_bounds__(256) void tail(const float* __restrict__ y2raw,
                                            const float* __restrict__ g2,
                                            const float* __restrict__ be2,
                                            const float* __restrict__ wf3,
                                            const float* __restrict__ bf3,
                                            float* __restrict__ out) {
    __shared__ float y2sm[64][33];
    __shared__ float scale2[32], shift2[32];
    int tid = threadIdx.x;
    for (int i = tid; i < 64 * 32; i += 256)
        y2sm[i >> 5][i & 31] = y2raw[i];
    __syncthreads();

    if (tid < 32) {
        float s = 0.f, s2 = 0.f;
        for (int b = 0; b < 64; b++) {
            float h = y2sm[b][tid];
            float hs = h / (1.0f + __expf(-h));
            s += hs;
            s2 += hs * hs;
        }
        float mu = s * (1.0f / 64.0f);
        float var = s2 * (1.0f / 64.0f) - mu * mu;
        float sc = rsqrtf(var + 1e-5f) * g2[tid];
        scale2[tid] = sc;
        shift2[tid] = be2[tid] - mu * sc;
    }
    __syncthreads();

    if (tid < 64) {
        float l0 = bf3[0], l1 = bf3[1];
        for (int k = 0; k < 32; k++) {
            float h = y2sm[tid][k];
            float hs = h / (1.0f + __expf(-h));
            float v = hs * scale2[k] + shift2[k];
            l0 += v * wf3[k * 2 + 0];
            l1 += v * wf3[k * 2 + 1];
        }
        float m = fmaxf(l0, l1);
        float e0 = __expf(l0 - m), e1 = __expf(l1 - m);
        float inv = 1.0f / (e0 + e1);
        out[tid * 2 + 0] = e0 * inv;
        out[tid * 2 + 1] = e1 * inv;
    }
}

// ---------------------------------------------------------------------------
extern "C" void kernel_launch(void* const* d_in, const int* in_sizes, int n_in,
                              void* d_out, int out_size, void* d_ws, size_t ws_size,
                              hipStream_t stream) {
    const float* x   = (const float*)d_in[0];
    const int*   ei  = (const int*)d_in[1];
    const float* w1  = (const float*)d_in[2];
    const float* b1  = (const float*)d_in[3];
    const float* w2  = (const float*)d_in[4];
    const float* b2  = (const float*)d_in[5];
    const float* pe  = (const float*)d_in[6];
    const float* wf1 = (const float*)d_in[7];
    const float* bf1 = (const float*)d_in[8];
    const float* g1  = (const float*)d_in[9];
    const float* be1 = (const float*)d_in[10];
    const float* wf2 = (const float*)d_in[11];
    const float* bf2 = (const float*)d_in[12];
    const float* g2  = (const float*)d_in[13];
    const float* be2 = (const float*)d_in[14];
    const float* wf3 = (const float*)d_in[15];
    const float* bf3 = (const float*)d_in[16];
    float* out = (float*)d_out;

    const int* srcp = ei;
    const int* dstp = ei + NEDGE;

    // workspace layout
    float* ws = (float*)d_ws;
    size_t off = 0;
    f16_t* h1h  = (f16_t*)(ws + off); off += (size_t)N_NODES * DH / 2;
    f16_t* ctxh = (f16_t*)(ws + off); off += (size_t)N_NODES * DH / 2;
    float* feat = ws + off; off += (size_t)BG * NSNAP * 512;
    bf16_t* h2bf = (bf16_t*)(ws + off); off += (size_t)N_NODES * DH / 2;
    bf16_t* h2T  = (bf16_t*)(ws + off); off += (size_t)N_NODES * DH / 2;
    f16_t* zh    = (f16_t*)(ws + off);  off += (size_t)N_NODES * XHP / 2;
    f16_t* xh    = (f16_t*)(ws + off);  off += (size_t)N_NODES * XHP / 2;
    float* y1raw = ws + off; off += 64 * 512;
    float* sscale = ws + off; off += 512;
    float* sshift = ws + off; off += 512;
    float* y2raw  = ws + off; off += 64 * 32;
    f16_t* w1hT  = (f16_t*)(ws + off);  off += (size_t)DH * KP / 2;
    f16_t* w12hT = (f16_t*)(ws + off);  off += (size_t)DH * KP / 2;
    float* bvec  = ws + off; off += DH;
    int* bucketTail = (int*)(ws + off); off += NBUCK;
    int* cnt  = (int*)(ws + off); off += N_NODES;
    unsigned int* rec = (unsigned int*)(ws + off); off += (size_t)NBUCK * BCAP;
    unsigned short* eidx = (unsigned short*)(ws + off);

    cvt_xh<<<(N_NODES * 21 + 255) / 256, 256, 0, stream>>>(x, xh, bucketTail);
    prep_w12<<<DIN + 1, 128, 0, stream>>>(w1, w2, b1, w1hT, w12hT, bvec);
    epart<<<NEDGE / EPB, 256, 0, stream>>>(srcp, dstp, bucketTail, rec);
    ebuild<<<NBUCK, 256, 0, stream>>>(rec, bucketTail, cnt, eidx);

    gin1<<<N_NODES / 32, 512, 0, stream>>>(xh, cnt, eidx, w1hT, b1, h1h, zh);
    gin2<<<N_NODES / 32, 512, 0, stream>>>(zh, cnt, eidx, w12hT, bvec, b2, pe, h2bf, h2T);
    attn_mfma<<<BG * 4, 512, 0, stream>>>(h2bf, h2T, ctxh);
    pooling<<<BG * NSNAP, 128, 0, stream>>>(h1h, ctxh, bf1, feat, y1raw);
    mlp1_splitk<<<dim3(4, 64), 256, 0, stream>>>(feat, wf1, y1raw);
    bn1s<<<4, 128, 0, stream>>>(y1raw, g1, be1, sscale, sshift);
    mlp2k<<<64, 256, 0, stream>>>(y1raw, sscale, sshift, wf2, bf2, y2raw);
    tail<<<1, 256, 0, stream>>>(y2raw, g2, be2, wf3, bf3, out);
}